// Round 2
// baseline (1726.727 us; speedup 1.0000x reference)
//
#include <hip/hip_runtime.h>
#include <hip/hip_bf16.h>

#define N_NODES 100000
#define N_EDGES 1600000
#define F_IN 128
#define HID 64
#define N_GRAPHS 1024

// ---------------- dual-path load helpers (wire dtype resolved at runtime) -----
__device__ __forceinline__ float loadf(const void* p, size_t i, int f32) {
    if (f32) return ((const float*)p)[i];
    return __bfloat162float(((const __hip_bfloat16*)p)[i]);
}
__device__ __forceinline__ int loadi(const void* p, size_t i, int i64) {
    if (i64) return (int)((const long long*)p)[i];
    return ((const int*)p)[i];
}

// ---------------- wire-format detector ----------------------------------------
// flags[0] = 1 if float tensors are fp32 on the wire (else bf16)
// flags[1] = 1 if int tensors are int64 on the wire (else int32)
__global__ void k_detect(const unsigned int* __restrict__ xw_,
                         const unsigned int* __restrict__ ei_,
                         int* __restrict__ flags) {
    __shared__ int cnt_f, cnt_i;
    if (threadIdx.x == 0) { cnt_f = 0; cnt_i = 0; }
    __syncthreads();
    // float test: low 16-bit half of word t. bf16-wire -> bf16(N(0,1)),
    // exponent field in [114,130]; fp32-wire -> random mantissa bits (~16% hit).
    unsigned int w = xw_[threadIdx.x];
    unsigned int e = (w >> 7) & 0xFFu;
    if (e >= 100u && e <= 140u) atomicAdd(&cnt_f, 1);
    // int test: odd 32-bit words. int64-wire -> all high words == 0.
    unsigned int iw = ei_[2 * threadIdx.x + 1];
    if (iw == 0u) atomicAdd(&cnt_i, 1);
    __syncthreads();
    if (threadIdx.x == 0) {
        flags[0] = (cnt_f < 180) ? 1 : 0;
        flags[1] = (cnt_i >= 128) ? 1 : 0;
    }
}

// ---------------- degree / norm ----------------
__global__ void k_set_deg(float* deg) {
    int i = blockIdx.x * blockDim.x + threadIdx.x;
    if (i < N_NODES) deg[i] = 1.0f;  // self-loop: deg = (#incoming) + 1
}

__global__ void k_count_deg(const void* __restrict__ ei, float* deg,
                            const int* __restrict__ flags) {
    int I64 = flags[1];
    int e = blockIdx.x * blockDim.x + threadIdx.x;
    if (e < N_EDGES) atomicAdd(&deg[loadi(ei, (size_t)N_EDGES + e, I64)], 1.0f);
}

__global__ void k_rsqrt(float* deg) {
    int i = blockIdx.x * blockDim.x + threadIdx.x;
    if (i < N_NODES) deg[i] = rsqrtf(deg[i]);
}

// ---------------- GEMM: x[N,128] @ W[128,64] -> out[N,64] f32 -----------------
__global__ void k_gemm_in(const void* __restrict__ x, const void* __restrict__ W,
                          float* __restrict__ out, const int* __restrict__ flags) {
    int F32 = flags[0];
    __shared__ float Ws[F_IN * HID];   // 32 KB
    __shared__ float xs[4 * F_IN];
    int t = threadIdx.x;
    for (int i = t; i < F_IN * HID; i += 256) Ws[i] = loadf(W, i, F32);
    int ngroups = (N_NODES + 3) / 4;
    for (int g = blockIdx.x; g < ngroups; g += gridDim.x) {
        __syncthreads();  // covers Ws load on first iter, xs reuse after
        int row0 = g * 4;
        for (int i = t; i < 4 * F_IN; i += 256) {
            int r = row0 + (i / F_IN);
            xs[i] = (r < N_NODES) ? loadf(x, (size_t)r * F_IN + (i % F_IN), F32) : 0.0f;
        }
        __syncthreads();
        int r = row0 + (t >> 6);
        int c = t & 63;
        if (r < N_NODES) {
            const float* xr = &xs[(t >> 6) * F_IN];
            float acc = 0.0f;
#pragma unroll
            for (int k = 0; k < F_IN; ++k) acc = fmaf(xr[k], Ws[k * HID + c], acc);
            out[(size_t)r * HID + c] = acc;
        }
    }
}

// ---------------- GEMM: h[N,64] (f32 ws) @ W[64,64] -> out[N,64] f32 ----------
__global__ void k_gemm_hid(const float* __restrict__ h, const void* __restrict__ W,
                           float* __restrict__ out, const int* __restrict__ flags) {
    int F32 = flags[0];
    __shared__ float Ws[HID * HID];   // 16 KB
    __shared__ float xs[4 * HID];
    int t = threadIdx.x;
    for (int i = t; i < HID * HID; i += 256) Ws[i] = loadf(W, i, F32);
    int ngroups = (N_NODES + 3) / 4;
    for (int g = blockIdx.x; g < ngroups; g += gridDim.x) {
        __syncthreads();
        int row0 = g * 4;
        for (int i = t; i < 4 * HID; i += 256) {
            int r = row0 + (i / HID);
            xs[i] = (r < N_NODES) ? h[(size_t)r * HID + (i % HID)] : 0.0f;
        }
        __syncthreads();
        int r = row0 + (t >> 6);
        int c = t & 63;
        if (r < N_NODES) {
            const float* xr = &xs[(t >> 6) * HID];
            float acc = 0.0f;
#pragma unroll
            for (int k = 0; k < HID; ++k) acc = fmaf(xr[k], Ws[k * HID + c], acc);
            out[(size_t)r * HID + c] = acc;
        }
    }
}

// ---------------- self-loop init: agg = xw * dis^2 ----------------------------
__global__ void k_selfloop(const float* __restrict__ xw, const float* __restrict__ dis,
                           float* __restrict__ agg) {
    int i = blockIdx.x * blockDim.x + threadIdx.x;
    if (i < N_NODES * HID) {
        float d = dis[i >> 6];
        agg[i] = xw[i] * d * d;
    }
}

// ---------------- edge scatter: agg[dst] += xw[src] * dis[src]*dis[dst] -------
__global__ void k_scatter(const void* __restrict__ ei,
                          const float* __restrict__ dis,
                          const float* __restrict__ xw,
                          float* __restrict__ agg,
                          const int* __restrict__ flags) {
    int I64 = flags[1];
    long long idx = (long long)blockIdx.x * blockDim.x + threadIdx.x;
    int e = (int)(idx >> 6);   // one wave per edge
    int f = (int)(idx & 63);   // lane = feature
    if (e < N_EDGES) {
        int s = loadi(ei, e, I64);
        int d = loadi(ei, (size_t)N_EDGES + e, I64);
        float norm = dis[s] * dis[d];
        atomicAdd(&agg[(size_t)d * HID + f], xw[(size_t)s * HID + f] * norm);
    }
}

// ---------------- bias (+ optional relu), in place ----------------------------
__global__ void k_bias_act(float* __restrict__ h, const void* __restrict__ b,
                           int do_relu, const int* __restrict__ flags) {
    int F32 = flags[0];
    int i = blockIdx.x * blockDim.x + threadIdx.x;
    if (i < N_NODES * HID) {
        float v = h[i] + loadf(b, i & (HID - 1), F32);
        h[i] = do_relu ? fmaxf(v, 0.0f) : v;
    }
}

// ---------------- pooling -----------------------------------------------------
__global__ void k_zero(float* p, int n) {
    int i = blockIdx.x * blockDim.x + threadIdx.x;
    if (i < n) p[i] = 0.0f;
}

__global__ void k_pool(const void* __restrict__ batch, const float* __restrict__ h,
                       float* __restrict__ pooled, float* __restrict__ counts,
                       const int* __restrict__ flags) {
    int I64 = flags[1];
    int idx = blockIdx.x * blockDim.x + threadIdx.x;
    int n = idx >> 6, f = idx & 63;
    if (n < N_NODES) {
        int g = loadi(batch, n, I64);
        atomicAdd(&pooled[(size_t)g * HID + f], h[(size_t)n * HID + f]);
        if (f == 0) atomicAdd(&counts[g], 1.0f);
    }
}

// ---------------- head: out[g] = (pooled[g]/cnt) . Wl + bl --------------------
__global__ void k_final(const float* __restrict__ pooled, const float* __restrict__ counts,
                        const void* __restrict__ Wl, const void* __restrict__ bl,
                        void* __restrict__ out, const int* __restrict__ flags) {
    int F32 = flags[0];
    int idx = blockIdx.x * blockDim.x + threadIdx.x;
    int g = idx >> 6, f = idx & 63;
    if (g < N_GRAPHS) {
        float c = fmaxf(counts[g], 1.0f);
        float v = (pooled[(size_t)g * HID + f] / c) * loadf(Wl, f, F32);
#pragma unroll
        for (int o = 32; o > 0; o >>= 1) v += __shfl_down(v, o, 64);
        if (f == 0) {
            float r = v + loadf(bl, 0, F32);
            if (F32) ((float*)out)[g] = r;
            else     ((__hip_bfloat16*)out)[g] = __float2bfloat16(r);
        }
    }
}

extern "C" void kernel_launch(void* const* d_in, const int* in_sizes, int n_in,
                              void* d_out, int out_size, void* d_ws, size_t ws_size,
                              hipStream_t stream) {
    const void* x  = d_in[0];
    const void* ei = d_in[1];
    const void* batch = d_in[2];
    const void* W1 = d_in[3];
    const void* b1 = d_in[4];
    const void* W2 = d_in[5];
    const void* b2 = d_in[6];
    const void* W3 = d_in[7];
    const void* b3 = d_in[8];
    const void* Wl = d_in[9];
    const void* bl = d_in[10];

    float* ws     = (float*)d_ws;
    float* dis    = ws;                      // 100352 (padded)
    float* bufA   = dis + 100352;            // 6.4M
    float* bufB   = bufA + 6400000;          // 6.4M
    float* pooled = bufB + 6400000;          // 65536
    float* counts = pooled + 65536;          // 1024
    int*   flags  = (int*)(counts + 1024);   // 2

    const int TB = 256;
    dim3 blk(TB);
    int gN   = (N_NODES + TB - 1) / TB;          // 391
    int gE   = (N_EDGES + TB - 1) / TB;          // 6250
    int gNH  = (N_NODES * HID + TB - 1) / TB;    // 25000
    int gEW  = (N_EDGES * 64) / TB;              // 400000
    int gPool = (N_NODES * 64 + TB - 1) / TB;    // 25000

    // wire-format detection
    k_detect<<<1, blk, 0, stream>>>((const unsigned int*)x, (const unsigned int*)ei, flags);

    // degrees -> dis
    k_set_deg<<<gN, blk, 0, stream>>>(dis);
    k_count_deg<<<gE, blk, 0, stream>>>(ei, dis, flags);
    k_rsqrt<<<gN, blk, 0, stream>>>(dis);

    // ---- layer 1 ----
    k_gemm_in<<<1024, blk, 0, stream>>>(x, W1, bufA, flags);
    k_selfloop<<<gNH, blk, 0, stream>>>(bufA, dis, bufB);
    k_scatter<<<gEW, blk, 0, stream>>>(ei, dis, bufA, bufB, flags);
    k_bias_act<<<gNH, blk, 0, stream>>>(bufB, b1, 1, flags);   // h1 in bufB

    // ---- layer 2 ----
    k_gemm_hid<<<1024, blk, 0, stream>>>(bufB, W2, bufA, flags);
    k_selfloop<<<gNH, blk, 0, stream>>>(bufA, dis, bufB);
    k_scatter<<<gEW, blk, 0, stream>>>(ei, dis, bufA, bufB, flags);
    k_bias_act<<<gNH, blk, 0, stream>>>(bufB, b2, 1, flags);   // h2 in bufB

    // ---- layer 3 ----
    k_gemm_hid<<<1024, blk, 0, stream>>>(bufB, W3, bufA, flags);
    k_selfloop<<<gNH, blk, 0, stream>>>(bufA, dis, bufB);
    k_scatter<<<gEW, blk, 0, stream>>>(ei, dis, bufA, bufB, flags);
    k_bias_act<<<gNH, blk, 0, stream>>>(bufB, b3, 0, flags);   // h3 in bufB (no relu)

    // ---- pool + head ----
    k_zero<<<(N_GRAPHS * HID + N_GRAPHS + TB - 1) / TB, blk, 0, stream>>>(pooled, N_GRAPHS * HID + N_GRAPHS);
    k_pool<<<gPool, blk, 0, stream>>>(batch, bufB, pooled, counts, flags);
    k_final<<<(N_GRAPHS * 64) / TB, blk, 0, stream>>>(pooled, counts, Wl, bl, d_out, flags);
}

// Round 3
// 942.457 us; speedup vs baseline: 1.8322x; 1.8322x over previous
//
#include <hip/hip_runtime.h>
#include <hip/hip_bf16.h>

#define N_NODES 100000
#define N_EDGES 1600000
#define F_IN 128
#define HID 64
#define N_GRAPHS 1024

// ---------------- dual-path load helpers (wire dtype resolved at runtime) -----
__device__ __forceinline__ float loadf(const void* p, size_t i, int f32) {
    if (f32) return ((const float*)p)[i];
    return __bfloat162float(((const __hip_bfloat16*)p)[i]);
}
__device__ __forceinline__ int loadi(const void* p, size_t i, int i64) {
    if (i64) return (int)((const long long*)p)[i];
    return ((const int*)p)[i];
}

// ---------------- wire-format detector ----------------------------------------
__global__ void k_detect(const unsigned int* __restrict__ xw_,
                         const unsigned int* __restrict__ ei_,
                         int* __restrict__ flags) {
    __shared__ int cnt_f, cnt_i;
    if (threadIdx.x == 0) { cnt_f = 0; cnt_i = 0; }
    __syncthreads();
    unsigned int w = xw_[threadIdx.x];
    unsigned int e = (w >> 7) & 0xFFu;
    if (e >= 100u && e <= 140u) atomicAdd(&cnt_f, 1);
    unsigned int iw = ei_[2 * threadIdx.x + 1];
    if (iw == 0u) atomicAdd(&cnt_i, 1);
    __syncthreads();
    if (threadIdx.x == 0) {
        flags[0] = (cnt_f < 180) ? 1 : 0;   // 1 => fp32 wire
        flags[1] = (cnt_i >= 128) ? 1 : 0;  // 1 => int64 wire
    }
}

// ---------------- small utility kernels ---------------------------------------
__global__ void k_zeroi(int* p, int n) {
    int i = blockIdx.x * blockDim.x + threadIdx.x;
    if (i < n) p[i] = 0;
}

__global__ void k_counti(const void* __restrict__ ei, int* __restrict__ cnt,
                         const int* __restrict__ flags) {
    int I64 = flags[1];
    int e = blockIdx.x * blockDim.x + threadIdx.x;
    if (e < N_EDGES) atomicAdd(&cnt[loadi(ei, (size_t)N_EDGES + e, I64)], 1);
}

__global__ void k_countb(const void* __restrict__ batch, int* __restrict__ gcnt,
                         const int* __restrict__ flags) {
    int I64 = flags[1];
    int n = blockIdx.x * blockDim.x + threadIdx.x;
    if (n < N_NODES) atomicAdd(&gcnt[loadi(batch, n, I64)], 1);
}

__global__ void k_disk(const int* __restrict__ cnt, float* __restrict__ dis) {
    int i = blockIdx.x * blockDim.x + threadIdx.x;
    if (i < N_NODES) dis[i] = rsqrtf((float)cnt[i] + 1.0f);  // self-loop degree
}

// single-block exclusive scan (n <= 1024*1024); out has n+1 entries
__global__ void k_scan(const int* __restrict__ in, int* __restrict__ out, int n) {
    __shared__ int sums[1024];
    int t = threadIdx.x;
    int chunk = (n + 1023) >> 10;
    int beg = t * chunk;
    int end = min(beg + chunk, n);
    int s = 0;
    for (int i = beg; i < end; ++i) s += in[i];
    sums[t] = s;
    __syncthreads();
    for (int off = 1; off < 1024; off <<= 1) {
        int v = (t >= off) ? sums[t - off] : 0;
        __syncthreads();
        sums[t] += v;
        __syncthreads();
    }
    int p = (t == 0) ? 0 : sums[t - 1];
    for (int i = beg; i < end; ++i) { out[i] = p; p += in[i]; }
    if (t == 1023) out[n] = sums[1023];
}

// bucket edges by dst. rp starts as exclusive row_ptr; after this kernel
// rp[d] == end-offset of node d (== original rp[d+1]).
__global__ void k_bucket(const void* __restrict__ ei, int* __restrict__ rp,
                         int* __restrict__ csr, const int* __restrict__ flags) {
    int I64 = flags[1];
    int e = blockIdx.x * blockDim.x + threadIdx.x;
    if (e < N_EDGES) {
        int s = loadi(ei, e, I64);
        int d = loadi(ei, (size_t)N_EDGES + e, I64);
        int pos = atomicAdd(&rp[d], 1);
        csr[pos] = s;
    }
}

// ---------------- GEMM: in[N,K] @ W[K,64] -> out[N,64] f32, scaled by dis[row] -
// Block 256 = 4 waves; each block-iter handles 16 rows (4 rows/wave).
// lane = (rsub 0..3, colgroup 0..15); each lane computes 4 consecutive cols
// via float4 ds_read of W. xs padded (+1) to spread banks.
template <int K>
__global__ __launch_bounds__(256) void k_gemm(const void* __restrict__ x,
                                              const void* __restrict__ W,
                                              const float* __restrict__ dis,
                                              float* __restrict__ out,
                                              const int* __restrict__ flags,
                                              int x_is_f32) {
    int Wf32 = flags[0];
    int xF32 = (x_is_f32 < 0) ? Wf32 : x_is_f32;
    __shared__ float Ws[K * HID];
    __shared__ float xs[16][K + 1];
    int t = threadIdx.x;
    for (int i = t; i < K * HID; i += 256) Ws[i] = loadf(W, i, Wf32);
    int wave = t >> 6, lane = t & 63;
    int rsub = lane >> 4, cg = lane & 15;
    int myrow = wave * 4 + rsub;
    int ngroups = (N_NODES + 15) / 16;
    for (int g = blockIdx.x; g < ngroups; g += gridDim.x) {
        __syncthreads();
        int row0 = g * 16;
        for (int i = t; i < 16 * K; i += 256) {
            int rr = i / K, cc = i % K;
            int r = row0 + rr;
            xs[rr][cc] = (r < N_NODES) ? loadf(x, (size_t)r * K + cc, xF32) : 0.0f;
        }
        __syncthreads();
        int r = row0 + myrow;
        if (r < N_NODES) {
            float a0 = 0, a1 = 0, a2 = 0, a3 = 0;
            const float* xr = xs[myrow];
            const float4* W4 = (const float4*)Ws;
#pragma unroll 8
            for (int k = 0; k < K; ++k) {
                float xv = xr[k];
                float4 wv = W4[k * 16 + cg];
                a0 = fmaf(xv, wv.x, a0);
                a1 = fmaf(xv, wv.y, a1);
                a2 = fmaf(xv, wv.z, a2);
                a3 = fmaf(xv, wv.w, a3);
            }
            float dn = dis[r];
            float4 o = make_float4(a0 * dn, a1 * dn, a2 * dn, a3 * dn);
            ((float4*)out)[(size_t)r * 16 + cg] = o;
        }
    }
}

// ---------------- fused gather + self-loop + bias + relu ----------------------
// h[d] = act( (sum_{s in in(d)} xws[s] + xws[d]) * dis[d] + b )
// where xws = (h_prev @ W) * dis[row]  (from k_gemm epilogue)
__global__ __launch_bounds__(256) void k_gather(const int* __restrict__ rp_end,
                                                const int* __restrict__ csr,
                                                const float* __restrict__ dis,
                                                const float* __restrict__ xws,
                                                const void* __restrict__ b,
                                                float* __restrict__ out,
                                                int do_relu,
                                                const int* __restrict__ flags) {
    int F32 = flags[0];
    int idx = blockIdx.x * 256 + threadIdx.x;
    int node = idx >> 6, f = idx & 63;
    if (node >= N_NODES) return;
    int start = (node == 0) ? 0 : rp_end[node - 1];
    int end = rp_end[node];
    float acc = 0.0f;
    int j = start;
    for (; j + 3 < end; j += 4) {
        int s0 = csr[j], s1 = csr[j + 1], s2 = csr[j + 2], s3 = csr[j + 3];
        float v0 = xws[(size_t)s0 * HID + f];
        float v1 = xws[(size_t)s1 * HID + f];
        float v2 = xws[(size_t)s2 * HID + f];
        float v3 = xws[(size_t)s3 * HID + f];
        acc += v0 + v1 + v2 + v3;
    }
    for (; j < end; ++j) acc += xws[(size_t)csr[j] * HID + f];
    float dn = dis[node];
    float v = fmaf(acc + xws[(size_t)node * HID + f], dn, loadf(b, f, F32));
    out[(size_t)node * HID + f] = do_relu ? fmaxf(v, 0.0f) : v;
}

// ---------------- fused mean-pool + linear head -------------------------------
// batch is sorted, so nodes of graph g are the contiguous range [gptr[g],gptr[g+1])
__global__ void k_pool_final(const int* __restrict__ gptr, const float* __restrict__ h,
                             const void* __restrict__ Wl, const void* __restrict__ bl,
                             void* __restrict__ out, const int* __restrict__ flags) {
    int F32 = flags[0];
    int g = blockIdx.x;
    int lane = threadIdx.x;  // 64
    int s = gptr[g], e = gptr[g + 1];
    float acc = 0.0f;
    for (int n = s; n < e; ++n) acc += h[(size_t)n * HID + lane];
    float cnt = fmaxf((float)(e - s), 1.0f);
    float v = (acc / cnt) * loadf(Wl, lane, F32);
#pragma unroll
    for (int o = 32; o > 0; o >>= 1) v += __shfl_down(v, o, 64);
    if (lane == 0) {
        float r = v + loadf(bl, 0, F32);
        if (F32) ((float*)out)[g] = r;
        else     ((__hip_bfloat16*)out)[g] = __float2bfloat16(r);
    }
}

extern "C" void kernel_launch(void* const* d_in, const int* in_sizes, int n_in,
                              void* d_out, int out_size, void* d_ws, size_t ws_size,
                              hipStream_t stream) {
    const void* x     = d_in[0];
    const void* ei    = d_in[1];
    const void* batch = d_in[2];
    const void* W1 = d_in[3];
    const void* b1 = d_in[4];
    const void* W2 = d_in[5];
    const void* b2 = d_in[6];
    const void* W3 = d_in[7];
    const void* b3 = d_in[8];
    const void* Wl = d_in[9];
    const void* bl = d_in[10];

    // workspace layout (~58.9 MB)
    float* dis  = (float*)d_ws;              // 100352
    int*   cnt  = (int*)(dis + 100352);      // 100352
    int*   rp   = cnt + 100352;              // 100352 (needs 100001)
    int*   csr  = rp + 100352;               // 1600000
    int*   gcnt = csr + 1600000;             // 1024
    int*   gptr = gcnt + 1024;               // 1056 (needs 1025)
    int*   flags = gptr + 1056;              // 16
    float* bufA = (float*)(flags + 16);      // 6400000 (16B-aligned)
    float* bufB = bufA + 6400000;            // 6400000

    const int TB = 256;
    dim3 blk(TB);
    int gN  = (N_NODES + TB - 1) / TB;       // 391
    int gE  = (N_EDGES + TB - 1) / TB;       // 6250
    int gNH = (N_NODES * HID) / TB;          // 25000

    // wire-format detection
    k_detect<<<1, blk, 0, stream>>>((const unsigned int*)x, (const unsigned int*)ei, flags);

    // degree counts, graph counts
    k_zeroi<<<(100352 + TB - 1) / TB, blk, 0, stream>>>(cnt, 100352);
    k_zeroi<<<4, blk, 0, stream>>>(gcnt, 1024);
    k_counti<<<gE, blk, 0, stream>>>(ei, cnt, flags);
    k_countb<<<gN, blk, 0, stream>>>(batch, gcnt, flags);
    k_disk<<<gN, blk, 0, stream>>>(cnt, dis);

    // CSR build
    k_scan<<<1, 1024, 0, stream>>>(cnt, rp, N_NODES);
    k_scan<<<1, 1024, 0, stream>>>(gcnt, gptr, N_GRAPHS);
    k_bucket<<<gE, blk, 0, stream>>>(ei, rp, csr, flags);  // rp becomes end-ptrs

    // ---- layer 1 ----
    k_gemm<F_IN><<<1024, blk, 0, stream>>>(x, W1, dis, bufA, flags, -1);
    k_gather<<<gNH, blk, 0, stream>>>(rp, csr, dis, bufA, b1, bufB, 1, flags);
    // ---- layer 2 ----
    k_gemm<HID><<<1024, blk, 0, stream>>>(bufB, W2, dis, bufA, flags, 1);
    k_gather<<<gNH, blk, 0, stream>>>(rp, csr, dis, bufA, b2, bufB, 1, flags);
    // ---- layer 3 ----
    k_gemm<HID><<<1024, blk, 0, stream>>>(bufB, W3, dis, bufA, flags, 1);
    k_gather<<<gNH, blk, 0, stream>>>(rp, csr, dis, bufA, b3, bufB, 0, flags);

    // ---- pool + head ----
    k_pool_final<<<N_GRAPHS, 64, 0, stream>>>(gptr, bufB, Wl, bl, d_out, flags);
}

// Round 4
// 751.944 us; speedup vs baseline: 2.2964x; 1.2534x over previous
//
#include <hip/hip_runtime.h>
#include <hip/hip_bf16.h>

#define N_NODES 100000
#define N_EDGES 1600000
#define F_IN 128
#define HID 64
#define N_GRAPHS 1024

// ---------------- dual-path load helpers (wire dtype resolved at runtime) -----
__device__ __forceinline__ float loadf(const void* p, size_t i, int f32) {
    if (f32) return ((const float*)p)[i];
    return __bfloat162float(((const __hip_bfloat16*)p)[i]);
}
__device__ __forceinline__ int loadi(const void* p, size_t i, int i64) {
    if (i64) return (int)((const long long*)p)[i];
    return ((const int*)p)[i];
}

// ---------------- wire-format detector ----------------------------------------
__global__ void k_detect(const unsigned int* __restrict__ xw_,
                         const unsigned int* __restrict__ ei_,
                         int* __restrict__ flags) {
    __shared__ int cnt_f, cnt_i;
    if (threadIdx.x == 0) { cnt_f = 0; cnt_i = 0; }
    __syncthreads();
    unsigned int w = xw_[threadIdx.x];
    unsigned int e = (w >> 7) & 0xFFu;
    if (e >= 100u && e <= 140u) atomicAdd(&cnt_f, 1);
    unsigned int iw = ei_[2 * threadIdx.x + 1];
    if (iw == 0u) atomicAdd(&cnt_i, 1);
    __syncthreads();
    if (threadIdx.x == 0) {
        flags[0] = (cnt_f < 180) ? 1 : 0;   // 1 => fp32 wire
        flags[1] = (cnt_i >= 128) ? 1 : 0;  // 1 => int64 wire
    }
}

// ---------------- small utility kernels ---------------------------------------
__global__ void k_zeroi(int* p, int n) {
    int i = blockIdx.x * blockDim.x + threadIdx.x;
    if (i < n) p[i] = 0;
}

__global__ void k_counti(const void* __restrict__ ei, int* __restrict__ cnt,
                         const int* __restrict__ flags) {
    int I64 = flags[1];
    int e = blockIdx.x * blockDim.x + threadIdx.x;
    if (e < N_EDGES) atomicAdd(&cnt[loadi(ei, (size_t)N_EDGES + e, I64)], 1);
}

__global__ void k_countb(const void* __restrict__ batch, int* __restrict__ gcnt,
                         const int* __restrict__ flags) {
    int I64 = flags[1];
    int n = blockIdx.x * blockDim.x + threadIdx.x;
    if (n < N_NODES) atomicAdd(&gcnt[loadi(batch, n, I64)], 1);
}

__global__ void k_disk(const int* __restrict__ cnt, float* __restrict__ dis) {
    int i = blockIdx.x * blockDim.x + threadIdx.x;
    if (i < N_NODES) dis[i] = rsqrtf((float)cnt[i] + 1.0f);  // self-loop degree
}

// ---------------- hierarchical exclusive scan (3 phases) ----------------------
// p1: per-block (256 elems) sums -> partial[b]
__global__ void k_scan_p1(const int* __restrict__ in, int* __restrict__ partial, int n) {
    __shared__ int s[256];
    int t = threadIdx.x;
    int i = blockIdx.x * 256 + t;
    s[t] = (i < n) ? in[i] : 0;
    __syncthreads();
    for (int off = 128; off > 0; off >>= 1) {
        if (t < off) s[t] += s[t + off];
        __syncthreads();
    }
    if (t == 0) partial[blockIdx.x] = s[0];
}

// p2: single block exclusive-scans partial[0..nb) in place (nb<=512);
// also writes grand total to out[n]
__global__ void k_scan_p2(int* __restrict__ partial, int nb,
                          int* __restrict__ out, int n) {
    __shared__ int s[512];
    int t = threadIdx.x;
    int v = (t < nb) ? partial[t] : 0;
    s[t] = v;
    __syncthreads();
    for (int off = 1; off < 512; off <<= 1) {
        int x = (t >= off) ? s[t - off] : 0;
        __syncthreads();
        s[t] += x;
        __syncthreads();
    }
    if (t < nb) partial[t] = s[t] - v;   // exclusive
    if (t == 511) out[n] = s[511];       // grand total
}

// p3: local exclusive scan + block offset
__global__ void k_scan_p3(const int* __restrict__ in, const int* __restrict__ partial,
                          int* __restrict__ out, int n) {
    __shared__ int s[256];
    int t = threadIdx.x;
    int i = blockIdx.x * 256 + t;
    int v = (i < n) ? in[i] : 0;
    s[t] = v;
    __syncthreads();
    for (int off = 1; off < 256; off <<= 1) {
        int x = (t >= off) ? s[t - off] : 0;
        __syncthreads();
        s[t] += x;
        __syncthreads();
    }
    if (i < n) out[i] = partial[blockIdx.x] + s[t] - v;
}

// bucket edges by dst. rp starts as exclusive row_ptr; after this kernel
// rp[d] == end-offset of node d.
__global__ void k_bucket(const void* __restrict__ ei, int* __restrict__ rp,
                         int* __restrict__ csr, const int* __restrict__ flags) {
    int I64 = flags[1];
    int e = blockIdx.x * blockDim.x + threadIdx.x;
    if (e < N_EDGES) {
        int s = loadi(ei, e, I64);
        int d = loadi(ei, (size_t)N_EDGES + e, I64);
        int pos = atomicAdd(&rp[d], 1);
        csr[pos] = s;
    }
}

// ---------------- GEMM: in[N,K] @ W[K,64] -> out[N,64] f32, scaled by dis[row] -
// Block 256 = 4 waves; each block-iter handles 16 rows (4 rows/wave).
// lane = (rsub 0..3)*16 + cg; each lane computes 4 consecutive cols.
// xs rows padded by one float4 (K+4 floats): rows 16(K+4) B apart -> the 4 rsub
// groups' b128 reads land on disjoint bank quads (no 4-way conflict).
template <int K>
__global__ __launch_bounds__(256) void k_gemm(const void* __restrict__ x,
                                              const void* __restrict__ W,
                                              const float* __restrict__ dis,
                                              float* __restrict__ out,
                                              const int* __restrict__ flags,
                                              int x_is_f32) {
    int Wf32 = flags[0];
    int xF32 = (x_is_f32 < 0) ? Wf32 : x_is_f32;
    __shared__ float Ws[K * HID];
    __shared__ float xs[16][K + 4];
    int t = threadIdx.x;
    for (int i = t; i < K * HID; i += 256) Ws[i] = loadf(W, i, Wf32);
    int wave = t >> 6, lane = t & 63;
    int rsub = lane >> 4, cg = lane & 15;
    int myrow = wave * 4 + rsub;
    int ngroups = (N_NODES + 15) / 16;
    for (int g = blockIdx.x; g < ngroups; g += gridDim.x) {
        __syncthreads();
        int row0 = g * 16;
        for (int i = t; i < 16 * K; i += 256) {
            int rr = i / K, cc = i % K;
            int r = row0 + rr;
            xs[rr][cc] = (r < N_NODES) ? loadf(x, (size_t)r * K + cc, xF32) : 0.0f;
        }
        __syncthreads();
        int r = row0 + myrow;
        if (r < N_NODES) {
            float a0 = 0, a1 = 0, a2 = 0, a3 = 0;
            const float4* xr4 = (const float4*)&xs[myrow][0];
            const float4* W4 = (const float4*)Ws;
#pragma unroll 4
            for (int k4 = 0; k4 < K / 4; ++k4) {
                float4 xv = xr4[k4];
                float4 w0 = W4[(4 * k4 + 0) * 16 + cg];
                float4 w1 = W4[(4 * k4 + 1) * 16 + cg];
                float4 w2 = W4[(4 * k4 + 2) * 16 + cg];
                float4 w3 = W4[(4 * k4 + 3) * 16 + cg];
                a0 = fmaf(xv.x, w0.x, a0); a1 = fmaf(xv.x, w0.y, a1);
                a2 = fmaf(xv.x, w0.z, a2); a3 = fmaf(xv.x, w0.w, a3);
                a0 = fmaf(xv.y, w1.x, a0); a1 = fmaf(xv.y, w1.y, a1);
                a2 = fmaf(xv.y, w1.z, a2); a3 = fmaf(xv.y, w1.w, a3);
                a0 = fmaf(xv.z, w2.x, a0); a1 = fmaf(xv.z, w2.y, a1);
                a2 = fmaf(xv.z, w2.z, a2); a3 = fmaf(xv.z, w2.w, a3);
                a0 = fmaf(xv.w, w3.x, a0); a1 = fmaf(xv.w, w3.y, a1);
                a2 = fmaf(xv.w, w3.z, a2); a3 = fmaf(xv.w, w3.w, a3);
            }
            float dn = dis[r];
            float4 o = make_float4(a0 * dn, a1 * dn, a2 * dn, a3 * dn);
            ((float4*)out)[(size_t)r * 16 + cg] = o;
        }
    }
}

// ---------------- fused gather + self-loop + bias + relu ----------------------
// Wave = node. lane = nsub*16 + f4: quarter-wave nsub loads neighbor j=start+it*4+nsub
// row-quarter f4 as float4; csr index prefetched; cross-quarter shfl reduce.
__global__ __launch_bounds__(256) void k_gather(const int* __restrict__ rp_end,
                                                const int* __restrict__ csr,
                                                const float* __restrict__ dis,
                                                const float* __restrict__ xws,
                                                const void* __restrict__ b,
                                                float* __restrict__ out,
                                                int do_relu,
                                                const int* __restrict__ flags) {
    int F32 = flags[0];
    int wave = threadIdx.x >> 6, lane = threadIdx.x & 63;
    int node = blockIdx.x * 4 + wave;
    if (node >= N_NODES) return;
    int f4 = lane & 15, nsub = lane >> 4;
    int start = (node == 0) ? 0 : rp_end[node - 1];
    int end = rp_end[node];
    const float4* x4 = (const float4*)xws;
    float ax = 0, ay = 0, az = 0, aw = 0;
    int j = start + nsub;
    if (j < end) {
        int s = csr[j];
        for (j += 4; j < end; j += 4) {
            int snext = csr[j];                       // prefetch next index
            float4 v = x4[(size_t)s * 16 + f4];
            ax += v.x; ay += v.y; az += v.z; aw += v.w;
            s = snext;
        }
        float4 v = x4[(size_t)s * 16 + f4];
        ax += v.x; ay += v.y; az += v.z; aw += v.w;
    }
    // reduce across the 4 quarter-waves (same f4 every 16 lanes)
    ax += __shfl_down(ax, 32, 64); ay += __shfl_down(ay, 32, 64);
    az += __shfl_down(az, 32, 64); aw += __shfl_down(aw, 32, 64);
    ax += __shfl_down(ax, 16, 64); ay += __shfl_down(ay, 16, 64);
    az += __shfl_down(az, 16, 64); aw += __shfl_down(aw, 16, 64);
    if (nsub == 0) {
        float4 self = x4[(size_t)node * 16 + f4];
        float dn = dis[node];
        float4 o;
        o.x = fmaf(ax + self.x, dn, loadf(b, 4 * f4 + 0, F32));
        o.y = fmaf(ay + self.y, dn, loadf(b, 4 * f4 + 1, F32));
        o.z = fmaf(az + self.z, dn, loadf(b, 4 * f4 + 2, F32));
        o.w = fmaf(aw + self.w, dn, loadf(b, 4 * f4 + 3, F32));
        if (do_relu) {
            o.x = fmaxf(o.x, 0.0f); o.y = fmaxf(o.y, 0.0f);
            o.z = fmaxf(o.z, 0.0f); o.w = fmaxf(o.w, 0.0f);
        }
        ((float4*)out)[(size_t)node * 16 + f4] = o;
    }
}

// ---------------- fused mean-pool + linear head -------------------------------
__global__ void k_pool_final(const int* __restrict__ gptr, const float* __restrict__ h,
                             const void* __restrict__ Wl, const void* __restrict__ bl,
                             void* __restrict__ out, const int* __restrict__ flags) {
    int F32 = flags[0];
    int g = blockIdx.x;
    int lane = threadIdx.x;  // 64
    int s = gptr[g], e = gptr[g + 1];
    float acc = 0.0f;
    for (int n = s; n < e; ++n) acc += h[(size_t)n * HID + lane];
    float cnt = fmaxf((float)(e - s), 1.0f);
    float v = (acc / cnt) * loadf(Wl, lane, F32);
#pragma unroll
    for (int o = 32; o > 0; o >>= 1) v += __shfl_down(v, o, 64);
    if (lane == 0) {
        float r = v + loadf(bl, 0, F32);
        if (F32) ((float*)out)[g] = r;
        else     ((__hip_bfloat16*)out)[g] = __float2bfloat16(r);
    }
}

extern "C" void kernel_launch(void* const* d_in, const int* in_sizes, int n_in,
                              void* d_out, int out_size, void* d_ws, size_t ws_size,
                              hipStream_t stream) {
    const void* x     = d_in[0];
    const void* ei    = d_in[1];
    const void* batch = d_in[2];
    const void* W1 = d_in[3];
    const void* b1 = d_in[4];
    const void* W2 = d_in[5];
    const void* b2 = d_in[6];
    const void* W3 = d_in[7];
    const void* b3 = d_in[8];
    const void* Wl = d_in[9];
    const void* bl = d_in[10];

    // workspace layout (~59.2 MB)
    float* dis   = (float*)d_ws;             // 100352
    int*   cnt   = (int*)(dis + 100352);     // 100352
    int*   rp    = cnt + 100352;             // 100352 (needs 100001)
    int*   csr   = rp + 100352;              // 1600000
    int*   gcnt  = csr + 1600000;            // 1024
    int*   gptr  = gcnt + 1024;              // 1056 (needs 1025)
    int*   partN = gptr + 1056;              // 512
    int*   partG = partN + 512;              // 512
    int*   flags = partG + 512;              // 16
    float* bufA  = (float*)(flags + 16);     // 6400000 (16B-aligned)
    float* bufB  = bufA + 6400000;           // 6400000

    const int TB = 256;
    dim3 blk(TB);
    int gN  = (N_NODES + TB - 1) / TB;       // 391
    int gE  = (N_EDGES + TB - 1) / TB;       // 6250
    int gG4 = (N_NODES + 3) / 4;             // 25000 (gather blocks)

    // wire-format detection
    k_detect<<<1, blk, 0, stream>>>((const unsigned int*)x, (const unsigned int*)ei, flags);

    // degree counts, graph counts
    k_zeroi<<<(100352 + TB - 1) / TB, blk, 0, stream>>>(cnt, 100352);
    k_zeroi<<<4, blk, 0, stream>>>(gcnt, 1024);
    k_counti<<<gE, blk, 0, stream>>>(ei, cnt, flags);
    k_countb<<<gN, blk, 0, stream>>>(batch, gcnt, flags);
    k_disk<<<gN, blk, 0, stream>>>(cnt, dis);

    // CSR build: hierarchical exclusive scans
    k_scan_p1<<<gN, blk, 0, stream>>>(cnt, partN, N_NODES);
    k_scan_p2<<<1, 512, 0, stream>>>(partN, gN, rp, N_NODES);
    k_scan_p3<<<gN, blk, 0, stream>>>(cnt, partN, rp, N_NODES);
    k_scan_p1<<<4, blk, 0, stream>>>(gcnt, partG, N_GRAPHS);
    k_scan_p2<<<1, 512, 0, stream>>>(partG, 4, gptr, N_GRAPHS);
    k_scan_p3<<<4, blk, 0, stream>>>(gcnt, partG, gptr, N_GRAPHS);
    k_bucket<<<gE, blk, 0, stream>>>(ei, rp, csr, flags);  // rp becomes end-ptrs

    // ---- layer 1 ----
    k_gemm<F_IN><<<1024, blk, 0, stream>>>(x, W1, dis, bufA, flags, -1);
    k_gather<<<gG4, blk, 0, stream>>>(rp, csr, dis, bufA, b1, bufB, 1, flags);
    // ---- layer 2 ----
    k_gemm<HID><<<1024, blk, 0, stream>>>(bufB, W2, dis, bufA, flags, 1);
    k_gather<<<gG4, blk, 0, stream>>>(rp, csr, dis, bufA, b2, bufB, 1, flags);
    // ---- layer 3 ----
    k_gemm<HID><<<1024, blk, 0, stream>>>(bufB, W3, dis, bufA, flags, 1);
    k_gather<<<gG4, blk, 0, stream>>>(rp, csr, dis, bufA, b3, bufB, 0, flags);

    // ---- pool + head ----
    k_pool_final<<<N_GRAPHS, 64, 0, stream>>>(gptr, bufB, Wl, bl, d_out, flags);
}

// Round 5
// 670.323 us; speedup vs baseline: 2.5760x; 1.1218x over previous
//
#include <hip/hip_runtime.h>
#include <hip/hip_bf16.h>

#define N_NODES 100000
#define N_EDGES 1600000
#define F_IN 128
#define HID 64
#define N_GRAPHS 1024

// ---------------- bf16 bit helpers --------------------------------------------
__device__ __forceinline__ unsigned short f2bf(float f) {
    __hip_bfloat16 h = __float2bfloat16(f);   // RNE
    return *reinterpret_cast<unsigned short*>(&h);
}
__device__ __forceinline__ float bf2f(unsigned int u) {
    return __uint_as_float(u << 16);
}

// ---------------- dual-path load helpers (wire dtype resolved at runtime) -----
__device__ __forceinline__ float loadf(const void* p, size_t i, int f32) {
    if (f32) return ((const float*)p)[i];
    return __bfloat162float(((const __hip_bfloat16*)p)[i]);
}
__device__ __forceinline__ int loadi(const void* p, size_t i, int i64) {
    if (i64) return (int)((const long long*)p)[i];
    return ((const int*)p)[i];
}

// ---------------- wire-format detector ----------------------------------------
__global__ void k_detect(const unsigned int* __restrict__ xw_,
                         const unsigned int* __restrict__ ei_,
                         int* __restrict__ flags) {
    __shared__ int cnt_f, cnt_i;
    if (threadIdx.x == 0) { cnt_f = 0; cnt_i = 0; }
    __syncthreads();
    unsigned int w = xw_[threadIdx.x];
    unsigned int e = (w >> 7) & 0xFFu;
    if (e >= 100u && e <= 140u) atomicAdd(&cnt_f, 1);
    unsigned int iw = ei_[2 * threadIdx.x + 1];
    if (iw == 0u) atomicAdd(&cnt_i, 1);
    __syncthreads();
    if (threadIdx.x == 0) {
        flags[0] = (cnt_f < 180) ? 1 : 0;   // 1 => fp32 wire
        flags[1] = (cnt_i >= 128) ? 1 : 0;  // 1 => int64 wire
    }
}

// ---------------- small utility kernels ---------------------------------------
__global__ void k_zeroi(int* p, int n) {
    int i = blockIdx.x * blockDim.x + threadIdx.x;
    if (i < n) p[i] = 0;
}

__global__ void k_counti(const void* __restrict__ ei, int* __restrict__ cnt,
                         const int* __restrict__ flags) {
    int I64 = flags[1];
    int e = blockIdx.x * blockDim.x + threadIdx.x;
    if (e < N_EDGES) atomicAdd(&cnt[loadi(ei, (size_t)N_EDGES + e, I64)], 1);
}

__global__ void k_countb(const void* __restrict__ batch, int* __restrict__ gcnt,
                         const int* __restrict__ flags) {
    int I64 = flags[1];
    int n = blockIdx.x * blockDim.x + threadIdx.x;
    if (n < N_NODES) atomicAdd(&gcnt[loadi(batch, n, I64)], 1);
}

__global__ void k_disk(const int* __restrict__ cnt, float* __restrict__ dis) {
    int i = blockIdx.x * blockDim.x + threadIdx.x;
    if (i < N_NODES) dis[i] = rsqrtf((float)cnt[i] + 1.0f);  // self-loop degree
}

// ---------------- hierarchical exclusive scan (3 phases) ----------------------
__global__ void k_scan_p1(const int* __restrict__ in, int* __restrict__ partial, int n) {
    __shared__ int s[256];
    int t = threadIdx.x;
    int i = blockIdx.x * 256 + t;
    s[t] = (i < n) ? in[i] : 0;
    __syncthreads();
    for (int off = 128; off > 0; off >>= 1) {
        if (t < off) s[t] += s[t + off];
        __syncthreads();
    }
    if (t == 0) partial[blockIdx.x] = s[0];
}

__global__ void k_scan_p2(int* __restrict__ partial, int nb,
                          int* __restrict__ out, int n) {
    __shared__ int s[512];
    int t = threadIdx.x;
    int v = (t < nb) ? partial[t] : 0;
    s[t] = v;
    __syncthreads();
    for (int off = 1; off < 512; off <<= 1) {
        int x = (t >= off) ? s[t - off] : 0;
        __syncthreads();
        s[t] += x;
        __syncthreads();
    }
    if (t < nb) partial[t] = s[t] - v;   // exclusive
    if (t == 511) out[n] = s[511];       // grand total
}

__global__ void k_scan_p3(const int* __restrict__ in, const int* __restrict__ partial,
                          int* __restrict__ out, int n) {
    __shared__ int s[256];
    int t = threadIdx.x;
    int i = blockIdx.x * 256 + t;
    int v = (i < n) ? in[i] : 0;
    s[t] = v;
    __syncthreads();
    for (int off = 1; off < 256; off <<= 1) {
        int x = (t >= off) ? s[t - off] : 0;
        __syncthreads();
        s[t] += x;
        __syncthreads();
    }
    if (i < n) out[i] = partial[blockIdx.x] + s[t] - v;
}

// bucket edges by dst. rp starts as exclusive row_ptr; after: rp[d] == end offset.
__global__ void k_bucket(const void* __restrict__ ei, int* __restrict__ rp,
                         int* __restrict__ csr, const int* __restrict__ flags) {
    int I64 = flags[1];
    int e = blockIdx.x * blockDim.x + threadIdx.x;
    if (e < N_EDGES) {
        int s = loadi(ei, e, I64);
        int d = loadi(ei, (size_t)N_EDGES + e, I64);
        int pos = atomicAdd(&rp[d], 1);
        csr[pos] = s;
    }
}

// ---------------- GEMM: in[N,K] @ W[K,64] -> out[N,64] bf16, scaled by dis[row]
// Block 256 = 4 waves; each block-iter handles 16 rows (4 rows/wave).
// lane = (rsub 0..3)*16 + cg; each lane computes 4 consecutive cols.
template <int K>
__global__ __launch_bounds__(256) void k_gemm(const void* __restrict__ x,
                                              const void* __restrict__ W,
                                              const float* __restrict__ dis,
                                              unsigned short* __restrict__ out,  // bf16 bits
                                              const int* __restrict__ flags,
                                              int x_is_f32) {
    int Wf32 = flags[0];
    int xF32 = (x_is_f32 < 0) ? Wf32 : x_is_f32;
    __shared__ float Ws[K * HID];
    __shared__ float xs[16][K + 4];
    int t = threadIdx.x;
    for (int i = t; i < K * HID; i += 256) Ws[i] = loadf(W, i, Wf32);
    int wave = t >> 6, lane = t & 63;
    int rsub = lane >> 4, cg = lane & 15;
    int myrow = wave * 4 + rsub;
    int ngroups = (N_NODES + 15) / 16;
    for (int g = blockIdx.x; g < ngroups; g += gridDim.x) {
        __syncthreads();
        int row0 = g * 16;
        // pair-vectorized staging (2 elems / thread / iter)
        for (int i = t; i < 16 * K / 2; i += 256) {
            int rr = (2 * i) / K, cc = (2 * i) % K;
            int r = row0 + rr;
            float v0 = 0.0f, v1 = 0.0f;
            if (r < N_NODES) {
                size_t base = ((size_t)r * K + cc) >> 1;
                if (xF32) {
                    float2 p = ((const float2*)x)[base];
                    v0 = p.x; v1 = p.y;
                } else {
                    unsigned int p = ((const unsigned int*)x)[base];
                    v0 = bf2f(p & 0xFFFFu); v1 = bf2f(p >> 16);
                }
            }
            xs[rr][cc] = v0; xs[rr][cc + 1] = v1;
        }
        __syncthreads();
        int r = row0 + myrow;
        if (r < N_NODES) {
            float a0 = 0, a1 = 0, a2 = 0, a3 = 0;
            const float4* xr4 = (const float4*)&xs[myrow][0];
            const float4* W4 = (const float4*)Ws;
#pragma unroll 4
            for (int k4 = 0; k4 < K / 4; ++k4) {
                float4 xv = xr4[k4];
                float4 w0 = W4[(4 * k4 + 0) * 16 + cg];
                float4 w1 = W4[(4 * k4 + 1) * 16 + cg];
                float4 w2 = W4[(4 * k4 + 2) * 16 + cg];
                float4 w3 = W4[(4 * k4 + 3) * 16 + cg];
                a0 = fmaf(xv.x, w0.x, a0); a1 = fmaf(xv.x, w0.y, a1);
                a2 = fmaf(xv.x, w0.z, a2); a3 = fmaf(xv.x, w0.w, a3);
                a0 = fmaf(xv.y, w1.x, a0); a1 = fmaf(xv.y, w1.y, a1);
                a2 = fmaf(xv.y, w1.z, a2); a3 = fmaf(xv.y, w1.w, a3);
                a0 = fmaf(xv.z, w2.x, a0); a1 = fmaf(xv.z, w2.y, a1);
                a2 = fmaf(xv.z, w2.z, a2); a3 = fmaf(xv.z, w2.w, a3);
                a0 = fmaf(xv.w, w3.x, a0); a1 = fmaf(xv.w, w3.y, a1);
                a2 = fmaf(xv.w, w3.z, a2); a3 = fmaf(xv.w, w3.w, a3);
            }
            float dn = dis[r];
            ushort4 o;
            o.x = f2bf(a0 * dn); o.y = f2bf(a1 * dn);
            o.z = f2bf(a2 * dn); o.w = f2bf(a3 * dn);
            ((ushort4*)out)[(size_t)r * 16 + cg] = o;
        }
    }
}

// ---------------- fused gather + self-loop + bias + relu ----------------------
// xws is bf16 (row = 64 bf16 = 128 B). Wave = node; quarter-wave nsub walks
// neighbors j = start+it*4+nsub, lane f4 reads ushort4 (4 feats).
__global__ __launch_bounds__(256) void k_gather(const int* __restrict__ rp_end,
                                                const int* __restrict__ csr,
                                                const float* __restrict__ dis,
                                                const unsigned short* __restrict__ xws,
                                                const void* __restrict__ b,
                                                float* __restrict__ out,
                                                int do_relu,
                                                const int* __restrict__ flags) {
    int F32 = flags[0];
    int wave = threadIdx.x >> 6, lane = threadIdx.x & 63;
    int node = blockIdx.x * 4 + wave;
    if (node >= N_NODES) return;
    int f4 = lane & 15, nsub = lane >> 4;
    int start = (node == 0) ? 0 : rp_end[node - 1];
    int end = rp_end[node];
    const ushort4* x4 = (const ushort4*)xws;
    float ax = 0, ay = 0, az = 0, aw = 0;
    int j = start + nsub;
    if (j < end) {
        int s = csr[j];
        for (j += 4; j < end; j += 4) {
            int snext = csr[j];                       // prefetch next index
            ushort4 v = x4[(size_t)s * 16 + f4];
            ax += bf2f(v.x); ay += bf2f(v.y); az += bf2f(v.z); aw += bf2f(v.w);
            s = snext;
        }
        ushort4 v = x4[(size_t)s * 16 + f4];
        ax += bf2f(v.x); ay += bf2f(v.y); az += bf2f(v.z); aw += bf2f(v.w);
    }
    // reduce across the 4 quarter-waves (same f4 every 16 lanes)
    ax += __shfl_down(ax, 32, 64); ay += __shfl_down(ay, 32, 64);
    az += __shfl_down(az, 32, 64); aw += __shfl_down(aw, 32, 64);
    ax += __shfl_down(ax, 16, 64); ay += __shfl_down(ay, 16, 64);
    az += __shfl_down(az, 16, 64); aw += __shfl_down(aw, 16, 64);
    if (nsub == 0) {
        ushort4 sv = x4[(size_t)node * 16 + f4];
        float dn = dis[node];
        float4 o;
        o.x = fmaf(ax + bf2f(sv.x), dn, loadf(b, 4 * f4 + 0, F32));
        o.y = fmaf(ay + bf2f(sv.y), dn, loadf(b, 4 * f4 + 1, F32));
        o.z = fmaf(az + bf2f(sv.z), dn, loadf(b, 4 * f4 + 2, F32));
        o.w = fmaf(aw + bf2f(sv.w), dn, loadf(b, 4 * f4 + 3, F32));
        if (do_relu) {
            o.x = fmaxf(o.x, 0.0f); o.y = fmaxf(o.y, 0.0f);
            o.z = fmaxf(o.z, 0.0f); o.w = fmaxf(o.w, 0.0f);
        }
        ((float4*)out)[(size_t)node * 16 + f4] = o;
    }
}

// ---------------- fused mean-pool + linear head -------------------------------
__global__ void k_pool_final(const int* __restrict__ gptr, const float* __restrict__ h,
                             const void* __restrict__ Wl, const void* __restrict__ bl,
                             void* __restrict__ out, const int* __restrict__ flags) {
    int F32 = flags[0];
    int g = blockIdx.x;
    int lane = threadIdx.x;  // 64
    int s = gptr[g], e = gptr[g + 1];
    float acc = 0.0f;
    for (int n = s; n < e; ++n) acc += h[(size_t)n * HID + lane];
    float cnt = fmaxf((float)(e - s), 1.0f);
    float v = (acc / cnt) * loadf(Wl, lane, F32);
#pragma unroll
    for (int o = 32; o > 0; o >>= 1) v += __shfl_down(v, o, 64);
    if (lane == 0) {
        float r = v + loadf(bl, 0, F32);
        if (F32) ((float*)out)[g] = r;
        else     ((__hip_bfloat16*)out)[g] = __float2bfloat16(r);
    }
}

extern "C" void kernel_launch(void* const* d_in, const int* in_sizes, int n_in,
                              void* d_out, int out_size, void* d_ws, size_t ws_size,
                              hipStream_t stream) {
    const void* x     = d_in[0];
    const void* ei    = d_in[1];
    const void* batch = d_in[2];
    const void* W1 = d_in[3];
    const void* b1 = d_in[4];
    const void* W2 = d_in[5];
    const void* b2 = d_in[6];
    const void* W3 = d_in[7];
    const void* b3 = d_in[8];
    const void* Wl = d_in[9];
    const void* bl = d_in[10];

    // workspace layout
    float* dis   = (float*)d_ws;             // 100352
    int*   cnt   = (int*)(dis + 100352);     // 100352
    int*   rp    = cnt + 100352;             // 100352 (needs 100001)
    int*   csr   = rp + 100352;              // 1600000
    int*   gcnt  = csr + 1600000;            // 1024
    int*   gptr  = gcnt + 1024;              // 1056 (needs 1025)
    int*   partN = gptr + 1056;              // 512
    int*   partG = partN + 512;              // 512
    int*   flags = partG + 512;              // 16
    unsigned short* bufA = (unsigned short*)(flags + 16);  // bf16 xws: 6.4M elems (12.8 MB)
    float* bufB  = (float*)(bufA + 6400000);               // fp32 h: 6.4M elems (25.6 MB)

    const int TB = 256;
    dim3 blk(TB);
    int gN  = (N_NODES + TB - 1) / TB;       // 391
    int gE  = (N_EDGES + TB - 1) / TB;       // 6250
    int gG4 = (N_NODES + 3) / 4;             // 25000 (gather blocks)

    // wire-format detection
    k_detect<<<1, blk, 0, stream>>>((const unsigned int*)x, (const unsigned int*)ei, flags);

    // degree counts, graph counts
    k_zeroi<<<(100352 + TB - 1) / TB, blk, 0, stream>>>(cnt, 100352);
    k_zeroi<<<4, blk, 0, stream>>>(gcnt, 1024);
    k_counti<<<gE, blk, 0, stream>>>(ei, cnt, flags);
    k_countb<<<gN, blk, 0, stream>>>(batch, gcnt, flags);
    k_disk<<<gN, blk, 0, stream>>>(cnt, dis);

    // CSR build: hierarchical exclusive scans
    k_scan_p1<<<gN, blk, 0, stream>>>(cnt, partN, N_NODES);
    k_scan_p2<<<1, 512, 0, stream>>>(partN, gN, rp, N_NODES);
    k_scan_p3<<<gN, blk, 0, stream>>>(cnt, partN, rp, N_NODES);
    k_scan_p1<<<4, blk, 0, stream>>>(gcnt, partG, N_GRAPHS);
    k_scan_p2<<<1, 512, 0, stream>>>(partG, 4, gptr, N_GRAPHS);
    k_scan_p3<<<4, blk, 0, stream>>>(gcnt, partG, gptr, N_GRAPHS);
    k_bucket<<<gE, blk, 0, stream>>>(ei, rp, csr, flags);  // rp becomes end-ptrs

    // ---- layer 1 ----
    k_gemm<F_IN><<<1024, blk, 0, stream>>>(x, W1, dis, bufA, flags, -1);
    k_gather<<<gG4, blk, 0, stream>>>(rp, csr, dis, bufA, b1, bufB, 1, flags);
    // ---- layer 2 ----
    k_gemm<HID><<<1024, blk, 0, stream>>>(bufB, W2, dis, bufA, flags, 1);
    k_gather<<<gG4, blk, 0, stream>>>(rp, csr, dis, bufA, b2, bufB, 1, flags);
    // ---- layer 3 ----
    k_gemm<HID><<<1024, blk, 0, stream>>>(bufB, W3, dis, bufA, flags, 1);
    k_gather<<<gG4, blk, 0, stream>>>(rp, csr, dis, bufA, b3, bufB, 0, flags);

    // ---- pool + head ----
    k_pool_final<<<N_GRAPHS, 64, 0, stream>>>(gptr, bufB, Wl, bl, d_out, flags);
}

// Round 6
// 669.621 us; speedup vs baseline: 2.5787x; 1.0010x over previous
//
#include <hip/hip_runtime.h>
#include <hip/hip_bf16.h>

#define N_NODES 100000
#define N_EDGES 1600000
#define F_IN 128
#define HID 64
#define N_GRAPHS 1024

// coarse dst-partition for CSR build
#define NB 64          // buckets allocated (49 used: dst>>11)
#define BCAP 40960     // per-bucket capacity (mean 32768 + 45 sigma)
#define BPB 32         // blocks per bucket in phase B

// ---------------- bf16 bit helpers --------------------------------------------
__device__ __forceinline__ unsigned short f2bf(float f) {
    __hip_bfloat16 h = __float2bfloat16(f);   // RNE
    return *reinterpret_cast<unsigned short*>(&h);
}
__device__ __forceinline__ float bf2f(unsigned int u) {
    return __uint_as_float(u << 16);
}

// ---------------- dual-path load helpers (wire dtype resolved at runtime) -----
__device__ __forceinline__ float loadf(const void* p, size_t i, int f32) {
    if (f32) return ((const float*)p)[i];
    return __bfloat162float(((const __hip_bfloat16*)p)[i]);
}
__device__ __forceinline__ int loadi(const void* p, size_t i, int i64) {
    if (i64) return (int)((const long long*)p)[i];
    return ((const int*)p)[i];
}

// ---------------- wire-format detector ----------------------------------------
__global__ void k_detect(const unsigned int* __restrict__ xw_,
                         const unsigned int* __restrict__ ei_,
                         int* __restrict__ flags) {
    __shared__ int cnt_f, cnt_i;
    if (threadIdx.x == 0) { cnt_f = 0; cnt_i = 0; }
    __syncthreads();
    unsigned int w = xw_[threadIdx.x];
    unsigned int e = (w >> 7) & 0xFFu;
    if (e >= 100u && e <= 140u) atomicAdd(&cnt_f, 1);
    unsigned int iw = ei_[2 * threadIdx.x + 1];
    if (iw == 0u) atomicAdd(&cnt_i, 1);
    __syncthreads();
    if (threadIdx.x == 0) {
        flags[0] = (cnt_f < 180) ? 1 : 0;   // 1 => fp32 wire
        flags[1] = (cnt_i >= 128) ? 1 : 0;  // 1 => int64 wire
    }
}

// ---------------- small utility kernels ---------------------------------------
__global__ void k_zeroi(int* p, int n) {
    int i = blockIdx.x * blockDim.x + threadIdx.x;
    if (i < n) p[i] = 0;
}

__global__ void k_counti(const void* __restrict__ ei, int* __restrict__ cnt,
                         const int* __restrict__ flags) {
    int I64 = flags[1];
    int e = blockIdx.x * blockDim.x + threadIdx.x;
    if (e < N_EDGES) atomicAdd(&cnt[loadi(ei, (size_t)N_EDGES + e, I64)], 1);
}

__global__ void k_countb(const void* __restrict__ batch, int* __restrict__ gcnt,
                         const int* __restrict__ flags) {
    int I64 = flags[1];
    int n = blockIdx.x * blockDim.x + threadIdx.x;
    if (n < N_NODES) atomicAdd(&gcnt[loadi(batch, n, I64)], 1);
}

__global__ void k_disk(const int* __restrict__ cnt, float* __restrict__ dis) {
    int i = blockIdx.x * blockDim.x + threadIdx.x;
    if (i < N_NODES) dis[i] = rsqrtf((float)cnt[i] + 1.0f);  // self-loop degree
}

// ---------------- hierarchical exclusive scan (3 phases) ----------------------
__global__ void k_scan_p1(const int* __restrict__ in, int* __restrict__ partial, int n) {
    __shared__ int s[256];
    int t = threadIdx.x;
    int i = blockIdx.x * 256 + t;
    s[t] = (i < n) ? in[i] : 0;
    __syncthreads();
    for (int off = 128; off > 0; off >>= 1) {
        if (t < off) s[t] += s[t + off];
        __syncthreads();
    }
    if (t == 0) partial[blockIdx.x] = s[0];
}

__global__ void k_scan_p2(int* __restrict__ partial, int nb,
                          int* __restrict__ out, int n) {
    __shared__ int s[512];
    int t = threadIdx.x;
    int v = (t < nb) ? partial[t] : 0;
    s[t] = v;
    __syncthreads();
    for (int off = 1; off < 512; off <<= 1) {
        int x = (t >= off) ? s[t - off] : 0;
        __syncthreads();
        s[t] += x;
        __syncthreads();
    }
    if (t < nb) partial[t] = s[t] - v;   // exclusive
    if (t == 511) out[n] = s[511];       // grand total
}

__global__ void k_scan_p3(const int* __restrict__ in, const int* __restrict__ partial,
                          int* __restrict__ out, int n) {
    __shared__ int s[256];
    int t = threadIdx.x;
    int i = blockIdx.x * 256 + t;
    int v = (i < n) ? in[i] : 0;
    s[t] = v;
    __syncthreads();
    for (int off = 1; off < 256; off <<= 1) {
        int x = (t >= off) ? s[t - off] : 0;
        __syncthreads();
        s[t] += x;
        __syncthreads();
    }
    if (i < n) out[i] = partial[blockIdx.x] + s[t] - v;
}

// ---------------- CSR build, phase A: coarse partition by dst>>11 -------------
// Block handles 1024 edges. LDS histogram rank + one global reserve per bucket.
// packed entry: (src << 11) | (dst & 2047)  -- 28 bits.
__global__ __launch_bounds__(256) void k_part(const void* __restrict__ ei,
                                              int* __restrict__ bcnt,
                                              unsigned int* __restrict__ packed,
                                              const int* __restrict__ flags) {
    int I64 = flags[1];
    __shared__ int hist[NB];
    __shared__ int base[NB];
    int t = threadIdx.x;
    if (t < NB) hist[t] = 0;
    __syncthreads();
    int e0 = blockIdx.x * 1024;
    int b[4], r[4];
    unsigned int pk[4];
    for (int it = 0; it < 4; ++it) {
        int e = e0 + it * 256 + t;
        b[it] = -1;
        if (e < N_EDGES) {
            int s = loadi(ei, e, I64);
            int d = loadi(ei, (size_t)N_EDGES + e, I64);
            b[it] = d >> 11;
            pk[it] = ((unsigned int)s << 11) | (unsigned int)(d & 2047);
            r[it] = atomicAdd(&hist[b[it]], 1);   // LDS rank
        }
    }
    __syncthreads();
    if (t < NB) base[t] = hist[t] ? atomicAdd(&bcnt[t], hist[t]) : 0;
    __syncthreads();
    for (int it = 0; it < 4; ++it) {
        if (b[it] >= 0) {
            int pos = base[b[it]] + r[it];
            if (pos < BCAP) packed[(size_t)b[it] * BCAP + pos] = pk[it];
        }
    }
}

// ---------------- CSR build, phase B: per-bucket scatter into csr -------------
// Blocks [b*BPB, (b+1)*BPB) handle bucket b; its csr window (~131 KB) stays hot.
__global__ __launch_bounds__(256) void k_scatcsr(const unsigned int* __restrict__ packed,
                                                 const int* __restrict__ bcnt,
                                                 int* __restrict__ rp,
                                                 int* __restrict__ csr) {
    int b = blockIdx.x / BPB, sub = blockIdx.x % BPB;
    int n = bcnt[b];
    if (n > BCAP) n = BCAP;
    const unsigned int* pb = packed + (size_t)b * BCAP;
    for (int i = sub * 256 + threadIdx.x; i < n; i += BPB * 256) {
        unsigned int p = pb[i];
        int s = (int)(p >> 11);
        int d = (b << 11) | (int)(p & 2047u);
        int pos = atomicAdd(&rp[d], 1);
        csr[pos] = s;
    }
}

// ---------------- GEMM: in[N,K] @ W[K,64] -> out[N,64] bf16, scaled by dis[row]
template <int K>
__global__ __launch_bounds__(256) void k_gemm(const void* __restrict__ x,
                                              const void* __restrict__ W,
                                              const float* __restrict__ dis,
                                              unsigned short* __restrict__ out,  // bf16 bits
                                              const int* __restrict__ flags,
                                              int x_is_f32) {
    int Wf32 = flags[0];
    int xF32 = (x_is_f32 < 0) ? Wf32 : x_is_f32;
    __shared__ float Ws[K * HID];
    __shared__ float xs[16][K + 4];
    int t = threadIdx.x;
    for (int i = t; i < K * HID; i += 256) Ws[i] = loadf(W, i, Wf32);
    int wave = t >> 6, lane = t & 63;
    int rsub = lane >> 4, cg = lane & 15;
    int myrow = wave * 4 + rsub;
    int ngroups = (N_NODES + 15) / 16;
    for (int g = blockIdx.x; g < ngroups; g += gridDim.x) {
        __syncthreads();
        int row0 = g * 16;
        for (int i = t; i < 16 * K / 2; i += 256) {
            int rr = (2 * i) / K, cc = (2 * i) % K;
            int r = row0 + rr;
            float v0 = 0.0f, v1 = 0.0f;
            if (r < N_NODES) {
                size_t base = ((size_t)r * K + cc) >> 1;
                if (xF32) {
                    float2 p = ((const float2*)x)[base];
                    v0 = p.x; v1 = p.y;
                } else {
                    unsigned int p = ((const unsigned int*)x)[base];
                    v0 = bf2f(p & 0xFFFFu); v1 = bf2f(p >> 16);
                }
            }
            xs[rr][cc] = v0; xs[rr][cc + 1] = v1;
        }
        __syncthreads();
        int r = row0 + myrow;
        if (r < N_NODES) {
            float a0 = 0, a1 = 0, a2 = 0, a3 = 0;
            const float4* xr4 = (const float4*)&xs[myrow][0];
            const float4* W4 = (const float4*)Ws;
#pragma unroll 4
            for (int k4 = 0; k4 < K / 4; ++k4) {
                float4 xv = xr4[k4];
                float4 w0 = W4[(4 * k4 + 0) * 16 + cg];
                float4 w1 = W4[(4 * k4 + 1) * 16 + cg];
                float4 w2 = W4[(4 * k4 + 2) * 16 + cg];
                float4 w3 = W4[(4 * k4 + 3) * 16 + cg];
                a0 = fmaf(xv.x, w0.x, a0); a1 = fmaf(xv.x, w0.y, a1);
                a2 = fmaf(xv.x, w0.z, a2); a3 = fmaf(xv.x, w0.w, a3);
                a0 = fmaf(xv.y, w1.x, a0); a1 = fmaf(xv.y, w1.y, a1);
                a2 = fmaf(xv.y, w1.z, a2); a3 = fmaf(xv.y, w1.w, a3);
                a0 = fmaf(xv.z, w2.x, a0); a1 = fmaf(xv.z, w2.y, a1);
                a2 = fmaf(xv.z, w2.z, a2); a3 = fmaf(xv.z, w2.w, a3);
                a0 = fmaf(xv.w, w3.x, a0); a1 = fmaf(xv.w, w3.y, a1);
                a2 = fmaf(xv.w, w3.z, a2); a3 = fmaf(xv.w, w3.w, a3);
            }
            float dn = dis[r];
            ushort4 o;
            o.x = f2bf(a0 * dn); o.y = f2bf(a1 * dn);
            o.z = f2bf(a2 * dn); o.w = f2bf(a3 * dn);
            ((ushort4*)out)[(size_t)r * 16 + cg] = o;
        }
    }
}

// ---------------- fused gather + self-loop + bias + relu ----------------------
__global__ __launch_bounds__(256) void k_gather(const int* __restrict__ rp_end,
                                                const int* __restrict__ csr,
                                                const float* __restrict__ dis,
                                                const unsigned short* __restrict__ xws,
                                                const void* __restrict__ b,
                                                float* __restrict__ out,
                                                int do_relu,
                                                const int* __restrict__ flags) {
    int F32 = flags[0];
    int wave = threadIdx.x >> 6, lane = threadIdx.x & 63;
    int node = blockIdx.x * 4 + wave;
    if (node >= N_NODES) return;
    int f4 = lane & 15, nsub = lane >> 4;
    int start = (node == 0) ? 0 : rp_end[node - 1];
    int end = rp_end[node];
    const ushort4* x4 = (const ushort4*)xws;
    float ax = 0, ay = 0, az = 0, aw = 0;
    int j = start + nsub;
    if (j < end) {
        int s = csr[j];
        for (j += 4; j < end; j += 4) {
            int snext = csr[j];                       // prefetch next index
            ushort4 v = x4[(size_t)s * 16 + f4];
            ax += bf2f(v.x); ay += bf2f(v.y); az += bf2f(v.z); aw += bf2f(v.w);
            s = snext;
        }
        ushort4 v = x4[(size_t)s * 16 + f4];
        ax += bf2f(v.x); ay += bf2f(v.y); az += bf2f(v.z); aw += bf2f(v.w);
    }
    ax += __shfl_down(ax, 32, 64); ay += __shfl_down(ay, 32, 64);
    az += __shfl_down(az, 32, 64); aw += __shfl_down(aw, 32, 64);
    ax += __shfl_down(ax, 16, 64); ay += __shfl_down(ay, 16, 64);
    az += __shfl_down(az, 16, 64); aw += __shfl_down(aw, 16, 64);
    if (nsub == 0) {
        ushort4 sv = x4[(size_t)node * 16 + f4];
        float dn = dis[node];
        float4 o;
        o.x = fmaf(ax + bf2f(sv.x), dn, loadf(b, 4 * f4 + 0, F32));
        o.y = fmaf(ay + bf2f(sv.y), dn, loadf(b, 4 * f4 + 1, F32));
        o.z = fmaf(az + bf2f(sv.z), dn, loadf(b, 4 * f4 + 2, F32));
        o.w = fmaf(aw + bf2f(sv.w), dn, loadf(b, 4 * f4 + 3, F32));
        if (do_relu) {
            o.x = fmaxf(o.x, 0.0f); o.y = fmaxf(o.y, 0.0f);
            o.z = fmaxf(o.z, 0.0f); o.w = fmaxf(o.w, 0.0f);
        }
        ((float4*)out)[(size_t)node * 16 + f4] = o;
    }
}

// ---------------- fused mean-pool + linear head -------------------------------
__global__ void k_pool_final(const int* __restrict__ gptr, const float* __restrict__ h,
                             const void* __restrict__ Wl, const void* __restrict__ bl,
                             void* __restrict__ out, const int* __restrict__ flags) {
    int F32 = flags[0];
    int g = blockIdx.x;
    int lane = threadIdx.x;  // 64
    int s = gptr[g], e = gptr[g + 1];
    float acc = 0.0f;
    for (int n = s; n < e; ++n) acc += h[(size_t)n * HID + lane];
    float cnt = fmaxf((float)(e - s), 1.0f);
    float v = (acc / cnt) * loadf(Wl, lane, F32);
#pragma unroll
    for (int o = 32; o > 0; o >>= 1) v += __shfl_down(v, o, 64);
    if (lane == 0) {
        float r = v + loadf(bl, 0, F32);
        if (F32) ((float*)out)[g] = r;
        else     ((__hip_bfloat16*)out)[g] = __float2bfloat16(r);
    }
}

extern "C" void kernel_launch(void* const* d_in, const int* in_sizes, int n_in,
                              void* d_out, int out_size, void* d_ws, size_t ws_size,
                              hipStream_t stream) {
    const void* x     = d_in[0];
    const void* ei    = d_in[1];
    const void* batch = d_in[2];
    const void* W1 = d_in[3];
    const void* b1 = d_in[4];
    const void* W2 = d_in[5];
    const void* b2 = d_in[6];
    const void* W3 = d_in[7];
    const void* b3 = d_in[8];
    const void* Wl = d_in[9];
    const void* bl = d_in[10];

    // workspace layout (~57 MB)
    float* dis   = (float*)d_ws;             // 100352
    int*   cnt   = (int*)(dis + 100352);     // 100352
    int*   rp    = cnt + 100352;             // 100352 (needs 100001)
    int*   csr   = rp + 100352;              // 1600000
    int*   gcnt  = csr + 1600000;            // 1024
    int*   gptr  = gcnt + 1024;              // 1056 (needs 1025)
    int*   partN = gptr + 1056;              // 512
    int*   partG = partN + 512;              // 512
    int*   bcnt  = partG + 512;              // 64
    int*   flags = bcnt + 64;                // 16
    unsigned int* packed = (unsigned int*)(flags + 16);    // NB*BCAP = 2.62M (10.5 MB)
    unsigned short* bufA = (unsigned short*)(packed + NB * BCAP);  // bf16 xws (12.8 MB)
    float* bufB  = (float*)(bufA + 6400000);               // fp32 h (25.6 MB)

    const int TB = 256;
    dim3 blk(TB);
    int gN  = (N_NODES + TB - 1) / TB;       // 391
    int gG4 = (N_NODES + 3) / 4;             // 25000 (gather blocks)

    // wire-format detection
    k_detect<<<1, blk, 0, stream>>>((const unsigned int*)x, (const unsigned int*)ei, flags);

    // degree counts, graph counts (bcnt zeroed alongside cnt region)
    k_zeroi<<<(100352 + TB - 1) / TB, blk, 0, stream>>>(cnt, 100352);
    k_zeroi<<<4, blk, 0, stream>>>(gcnt, 1024);
    k_zeroi<<<1, blk, 0, stream>>>(bcnt, NB);
    k_counti<<<(N_EDGES + TB - 1) / TB, blk, 0, stream>>>(ei, cnt, flags);
    k_countb<<<gN, blk, 0, stream>>>(batch, gcnt, flags);
    k_disk<<<gN, blk, 0, stream>>>(cnt, dis);

    // CSR build: scans + two-phase partition
    k_scan_p1<<<gN, blk, 0, stream>>>(cnt, partN, N_NODES);
    k_scan_p2<<<1, 512, 0, stream>>>(partN, gN, rp, N_NODES);
    k_scan_p3<<<gN, blk, 0, stream>>>(cnt, partN, rp, N_NODES);
    k_scan_p1<<<4, blk, 0, stream>>>(gcnt, partG, N_GRAPHS);
    k_scan_p2<<<1, 512, 0, stream>>>(partG, 4, gptr, N_GRAPHS);
    k_scan_p3<<<4, blk, 0, stream>>>(gcnt, partG, gptr, N_GRAPHS);
    k_part<<<(N_EDGES + 1023) / 1024, blk, 0, stream>>>(ei, bcnt, packed, flags);
    k_scatcsr<<<NB * BPB, blk, 0, stream>>>(packed, bcnt, rp, csr);  // rp -> end-ptrs

    // ---- layer 1 ----
    k_gemm<F_IN><<<1024, blk, 0, stream>>>(x, W1, dis, bufA, flags, -1);
    k_gather<<<gG4, blk, 0, stream>>>(rp, csr, dis, bufA, b1, bufB, 1, flags);
    // ---- layer 2 ----
    k_gemm<HID><<<1024, blk, 0, stream>>>(bufB, W2, dis, bufA, flags, 1);
    k_gather<<<gG4, blk, 0, stream>>>(rp, csr, dis, bufA, b2, bufB, 1, flags);
    // ---- layer 3 ----
    k_gemm<HID><<<1024, blk, 0, stream>>>(bufB, W3, dis, bufA, flags, 1);
    k_gather<<<gG4, blk, 0, stream>>>(rp, csr, dis, bufA, b3, bufB, 0, flags);

    // ---- pool + head ----
    k_pool_final<<<N_GRAPHS, 64, 0, stream>>>(gptr, bufB, Wl, bl, d_out, flags);
}

// Round 7
// 578.753 us; speedup vs baseline: 2.9835x; 1.1570x over previous
//
#include <hip/hip_runtime.h>
#include <hip/hip_bf16.h>

#define N_NODES 100000
#define N_EDGES 1600000
#define F_IN 128
#define HID 64
#define N_GRAPHS 1024

// coarse dst-partition for CSR build
#define NB 64          // buckets allocated (49 used: dst>>11)
#define BCAP 40960     // per-bucket capacity (mean 32768 + 45 sigma)
#define BPB 32         // blocks per bucket in phase B

// ---------------- bf16 bit helpers --------------------------------------------
__device__ __forceinline__ unsigned short f2bf(float f) {
    __hip_bfloat16 h = __float2bfloat16(f);   // RNE
    return *reinterpret_cast<unsigned short*>(&h);
}
__device__ __forceinline__ float bf2f(unsigned int u) {
    return __uint_as_float(u << 16);
}

// ---------------- dual-path load helpers (wire dtype resolved at runtime) -----
__device__ __forceinline__ float loadf(const void* p, size_t i, int f32) {
    if (f32) return ((const float*)p)[i];
    return __bfloat162float(((const __hip_bfloat16*)p)[i]);
}
__device__ __forceinline__ int loadi(const void* p, size_t i, int i64) {
    if (i64) return (int)((const long long*)p)[i];
    return ((const int*)p)[i];
}

// ---------------- wire-format detector ----------------------------------------
__global__ void k_detect(const unsigned int* __restrict__ xw_,
                         const unsigned int* __restrict__ ei_,
                         int* __restrict__ flags) {
    __shared__ int cnt_f, cnt_i;
    if (threadIdx.x == 0) { cnt_f = 0; cnt_i = 0; }
    __syncthreads();
    unsigned int w = xw_[threadIdx.x];
    unsigned int e = (w >> 7) & 0xFFu;
    if (e >= 100u && e <= 140u) atomicAdd(&cnt_f, 1);
    unsigned int iw = ei_[2 * threadIdx.x + 1];
    if (iw == 0u) atomicAdd(&cnt_i, 1);
    __syncthreads();
    if (threadIdx.x == 0) {
        flags[0] = (cnt_f < 180) ? 1 : 0;   // 1 => fp32 wire
        flags[1] = (cnt_i >= 128) ? 1 : 0;  // 1 => int64 wire
    }
}

// ---------------- small utility kernels ---------------------------------------
__global__ void k_zeroi(int* p, int n) {
    int i = blockIdx.x * blockDim.x + threadIdx.x;
    if (i < n) p[i] = 0;
}

__global__ void k_countb(const void* __restrict__ batch, int* __restrict__ gcnt,
                         const int* __restrict__ flags) {
    int I64 = flags[1];
    int n = blockIdx.x * blockDim.x + threadIdx.x;
    if (n < N_NODES) atomicAdd(&gcnt[loadi(batch, n, I64)], 1);
}

__global__ void k_disk(const int* __restrict__ cnt, float* __restrict__ dis) {
    int i = blockIdx.x * blockDim.x + threadIdx.x;
    if (i < N_NODES) dis[i] = rsqrtf((float)cnt[i] + 1.0f);  // self-loop degree
}

// ---------------- hierarchical exclusive scan (3 phases) ----------------------
__global__ void k_scan_p1(const int* __restrict__ in, int* __restrict__ partial, int n) {
    __shared__ int s[256];
    int t = threadIdx.x;
    int i = blockIdx.x * 256 + t;
    s[t] = (i < n) ? in[i] : 0;
    __syncthreads();
    for (int off = 128; off > 0; off >>= 1) {
        if (t < off) s[t] += s[t + off];
        __syncthreads();
    }
    if (t == 0) partial[blockIdx.x] = s[0];
}

__global__ void k_scan_p2(int* __restrict__ partial, int nb,
                          int* __restrict__ out, int n) {
    __shared__ int s[512];
    int t = threadIdx.x;
    int v = (t < nb) ? partial[t] : 0;
    s[t] = v;
    __syncthreads();
    for (int off = 1; off < 512; off <<= 1) {
        int x = (t >= off) ? s[t - off] : 0;
        __syncthreads();
        s[t] += x;
        __syncthreads();
    }
    if (t < nb) partial[t] = s[t] - v;   // exclusive
    if (t == 511) out[n] = s[511];       // grand total
}

__global__ void k_scan_p3(const int* __restrict__ in, const int* __restrict__ partial,
                          int* __restrict__ out, int n) {
    __shared__ int s[256];
    int t = threadIdx.x;
    int i = blockIdx.x * 256 + t;
    int v = (i < n) ? in[i] : 0;
    s[t] = v;
    __syncthreads();
    for (int off = 1; off < 256; off <<= 1) {
        int x = (t >= off) ? s[t - off] : 0;
        __syncthreads();
        s[t] += x;
        __syncthreads();
    }
    if (i < n) out[i] = partial[blockIdx.x] + s[t] - v;
}

// ---------------- CSR build, phase A: coarse partition by dst>>11 -------------
// Block handles 1024 edges. LDS histogram rank + one global reserve per bucket.
// packed entry: (src << 11) | (dst & 2047)  -- 28 bits.
__global__ __launch_bounds__(256) void k_part(const void* __restrict__ ei,
                                              int* __restrict__ bcnt,
                                              unsigned int* __restrict__ packed,
                                              const int* __restrict__ flags) {
    int I64 = flags[1];
    __shared__ int hist[NB];
    __shared__ int base[NB];
    int t = threadIdx.x;
    if (t < NB) hist[t] = 0;
    __syncthreads();
    int e0 = blockIdx.x * 1024;
    int b[4], r[4];
    unsigned int pk[4];
    for (int it = 0; it < 4; ++it) {
        int e = e0 + it * 256 + t;
        b[it] = -1;
        if (e < N_EDGES) {
            int s = loadi(ei, e, I64);
            int d = loadi(ei, (size_t)N_EDGES + e, I64);
            b[it] = d >> 11;
            pk[it] = ((unsigned int)s << 11) | (unsigned int)(d & 2047);
            r[it] = atomicAdd(&hist[b[it]], 1);   // LDS rank
        }
    }
    __syncthreads();
    if (t < NB) base[t] = hist[t] ? atomicAdd(&bcnt[t], hist[t]) : 0;
    __syncthreads();
    for (int it = 0; it < 4; ++it) {
        if (b[it] >= 0) {
            int pos = base[b[it]] + r[it];
            if (pos < BCAP) packed[(size_t)b[it] * BCAP + pos] = pk[it];
        }
    }
}

// ---------------- in-degree from packed: per-bucket LDS histogram -------------
// One block per bucket; 2048-bin LDS histogram; plain coalesced stores to cnt.
__global__ __launch_bounds__(1024) void k_hist(const unsigned int* __restrict__ packed,
                                               const int* __restrict__ bcnt,
                                               int* __restrict__ cnt) {
    __shared__ int hist[2048];
    int b = blockIdx.x;
    int n = bcnt[b];
    if (n > BCAP) n = BCAP;
    for (int i = threadIdx.x; i < 2048; i += 1024) hist[i] = 0;
    __syncthreads();
    const unsigned int* pb = packed + (size_t)b * BCAP;
    for (int i = threadIdx.x; i < n; i += 1024)
        atomicAdd(&hist[pb[i] & 2047u], 1);
    __syncthreads();
    int nbase = b << 11;
    for (int i = threadIdx.x; i < 2048; i += 1024) {
        int node = nbase + i;
        if (node < N_NODES) cnt[node] = hist[i];
    }
}

// ---------------- CSR build, phase B: per-bucket scatter into csr -------------
// XCD-pinned: blockIdx%8 selects XCD (round-robin dispatch heuristic); all 32
// blocks of a bucket share one XCD so its csr window lives in ONE L2 and each
// 64B line is written back once (kills the 95 MB cross-XCD write amplification).
__global__ __launch_bounds__(256) void k_scatcsr(const unsigned int* __restrict__ packed,
                                                 const int* __restrict__ bcnt,
                                                 int* __restrict__ rp,
                                                 int* __restrict__ csr) {
    int xcd = blockIdx.x & 7;
    int m = blockIdx.x >> 3;          // 0..255
    int b = 8 * (m / BPB) + xcd;      // all BPB blocks of bucket b on one XCD
    int sub = m % BPB;
    int n = bcnt[b];
    if (n > BCAP) n = BCAP;
    const unsigned int* pb = packed + (size_t)b * BCAP;
    for (int i = sub * 256 + threadIdx.x; i < n; i += BPB * 256) {
        unsigned int p = pb[i];
        int s = (int)(p >> 11);
        int d = (b << 11) | (int)(p & 2047u);
        int pos = atomicAdd(&rp[d], 1);
        csr[pos] = s;
    }
}

// ---------------- GEMM: in[N,K] @ W[K,64] -> out[N,64] bf16, scaled by dis[row]
template <int K>
__global__ __launch_bounds__(256) void k_gemm(const void* __restrict__ x,
                                              const void* __restrict__ W,
                                              const float* __restrict__ dis,
                                              unsigned short* __restrict__ out,  // bf16 bits
                                              const int* __restrict__ flags,
                                              int x_is_f32) {
    int Wf32 = flags[0];
    int xF32 = (x_is_f32 < 0) ? Wf32 : x_is_f32;
    __shared__ float Ws[K * HID];
    __shared__ float xs[16][K + 4];
    int t = threadIdx.x;
    for (int i = t; i < K * HID; i += 256) Ws[i] = loadf(W, i, Wf32);
    int wave = t >> 6, lane = t & 63;
    int rsub = lane >> 4, cg = lane & 15;
    int myrow = wave * 4 + rsub;
    int ngroups = (N_NODES + 15) / 16;
    for (int g = blockIdx.x; g < ngroups; g += gridDim.x) {
        __syncthreads();
        int row0 = g * 16;
        for (int i = t; i < 16 * K / 2; i += 256) {
            int rr = (2 * i) / K, cc = (2 * i) % K;
            int r = row0 + rr;
            float v0 = 0.0f, v1 = 0.0f;
            if (r < N_NODES) {
                size_t base = ((size_t)r * K + cc) >> 1;
                if (xF32) {
                    float2 p = ((const float2*)x)[base];
                    v0 = p.x; v1 = p.y;
                } else {
                    unsigned int p = ((const unsigned int*)x)[base];
                    v0 = bf2f(p & 0xFFFFu); v1 = bf2f(p >> 16);
                }
            }
            xs[rr][cc] = v0; xs[rr][cc + 1] = v1;
        }
        __syncthreads();
        int r = row0 + myrow;
        if (r < N_NODES) {
            float a0 = 0, a1 = 0, a2 = 0, a3 = 0;
            const float4* xr4 = (const float4*)&xs[myrow][0];
            const float4* W4 = (const float4*)Ws;
#pragma unroll 4
            for (int k4 = 0; k4 < K / 4; ++k4) {
                float4 xv = xr4[k4];
                float4 w0 = W4[(4 * k4 + 0) * 16 + cg];
                float4 w1 = W4[(4 * k4 + 1) * 16 + cg];
                float4 w2 = W4[(4 * k4 + 2) * 16 + cg];
                float4 w3 = W4[(4 * k4 + 3) * 16 + cg];
                a0 = fmaf(xv.x, w0.x, a0); a1 = fmaf(xv.x, w0.y, a1);
                a2 = fmaf(xv.x, w0.z, a2); a3 = fmaf(xv.x, w0.w, a3);
                a0 = fmaf(xv.y, w1.x, a0); a1 = fmaf(xv.y, w1.y, a1);
                a2 = fmaf(xv.y, w1.z, a2); a3 = fmaf(xv.y, w1.w, a3);
                a0 = fmaf(xv.z, w2.x, a0); a1 = fmaf(xv.z, w2.y, a1);
                a2 = fmaf(xv.z, w2.z, a2); a3 = fmaf(xv.z, w2.w, a3);
                a0 = fmaf(xv.w, w3.x, a0); a1 = fmaf(xv.w, w3.y, a1);
                a2 = fmaf(xv.w, w3.z, a2); a3 = fmaf(xv.w, w3.w, a3);
            }
            float dn = dis[r];
            ushort4 o;
            o.x = f2bf(a0 * dn); o.y = f2bf(a1 * dn);
            o.z = f2bf(a2 * dn); o.w = f2bf(a3 * dn);
            ((ushort4*)out)[(size_t)r * 16 + cg] = o;
        }
    }
}

// ---------------- fused gather + self-loop + bias + relu ----------------------
__global__ __launch_bounds__(256) void k_gather(const int* __restrict__ rp_end,
                                                const int* __restrict__ csr,
                                                const float* __restrict__ dis,
                                                const unsigned short* __restrict__ xws,
                                                const void* __restrict__ b,
                                                float* __restrict__ out,
                                                int do_relu,
                                                const int* __restrict__ flags) {
    int F32 = flags[0];
    int wave = threadIdx.x >> 6, lane = threadIdx.x & 63;
    int node = blockIdx.x * 4 + wave;
    if (node >= N_NODES) return;
    int f4 = lane & 15, nsub = lane >> 4;
    int start = (node == 0) ? 0 : rp_end[node - 1];
    int end = rp_end[node];
    const ushort4* x4 = (const ushort4*)xws;
    float ax = 0, ay = 0, az = 0, aw = 0;
    int j = start + nsub;
    if (j < end) {
        int s = csr[j];
        for (j += 4; j < end; j += 4) {
            int snext = csr[j];                       // prefetch next index
            ushort4 v = x4[(size_t)s * 16 + f4];
            ax += bf2f(v.x); ay += bf2f(v.y); az += bf2f(v.z); aw += bf2f(v.w);
            s = snext;
        }
        ushort4 v = x4[(size_t)s * 16 + f4];
        ax += bf2f(v.x); ay += bf2f(v.y); az += bf2f(v.z); aw += bf2f(v.w);
    }
    ax += __shfl_down(ax, 32, 64); ay += __shfl_down(ay, 32, 64);
    az += __shfl_down(az, 32, 64); aw += __shfl_down(aw, 32, 64);
    ax += __shfl_down(ax, 16, 64); ay += __shfl_down(ay, 16, 64);
    az += __shfl_down(az, 16, 64); aw += __shfl_down(aw, 16, 64);
    if (nsub == 0) {
        ushort4 sv = x4[(size_t)node * 16 + f4];
        float dn = dis[node];
        float4 o;
        o.x = fmaf(ax + bf2f(sv.x), dn, loadf(b, 4 * f4 + 0, F32));
        o.y = fmaf(ay + bf2f(sv.y), dn, loadf(b, 4 * f4 + 1, F32));
        o.z = fmaf(az + bf2f(sv.z), dn, loadf(b, 4 * f4 + 2, F32));
        o.w = fmaf(aw + bf2f(sv.w), dn, loadf(b, 4 * f4 + 3, F32));
        if (do_relu) {
            o.x = fmaxf(o.x, 0.0f); o.y = fmaxf(o.y, 0.0f);
            o.z = fmaxf(o.z, 0.0f); o.w = fmaxf(o.w, 0.0f);
        }
        ((float4*)out)[(size_t)node * 16 + f4] = o;
    }
}

// ---------------- fused mean-pool + linear head -------------------------------
__global__ void k_pool_final(const int* __restrict__ gptr, const float* __restrict__ h,
                             const void* __restrict__ Wl, const void* __restrict__ bl,
                             void* __restrict__ out, const int* __restrict__ flags) {
    int F32 = flags[0];
    int g = blockIdx.x;
    int lane = threadIdx.x;  // 64
    int s = gptr[g], e = gptr[g + 1];
    float acc = 0.0f;
    for (int n = s; n < e; ++n) acc += h[(size_t)n * HID + lane];
    float cnt = fmaxf((float)(e - s), 1.0f);
    float v = (acc / cnt) * loadf(Wl, lane, F32);
#pragma unroll
    for (int o = 32; o > 0; o >>= 1) v += __shfl_down(v, o, 64);
    if (lane == 0) {
        float r = v + loadf(bl, 0, F32);
        if (F32) ((float*)out)[g] = r;
        else     ((__hip_bfloat16*)out)[g] = __float2bfloat16(r);
    }
}

extern "C" void kernel_launch(void* const* d_in, const int* in_sizes, int n_in,
                              void* d_out, int out_size, void* d_ws, size_t ws_size,
                              hipStream_t stream) {
    const void* x     = d_in[0];
    const void* ei    = d_in[1];
    const void* batch = d_in[2];
    const void* W1 = d_in[3];
    const void* b1 = d_in[4];
    const void* W2 = d_in[5];
    const void* b2 = d_in[6];
    const void* W3 = d_in[7];
    const void* b3 = d_in[8];
    const void* Wl = d_in[9];
    const void* bl = d_in[10];

    // workspace layout (~57 MB)
    float* dis   = (float*)d_ws;             // 100352
    int*   cnt   = (int*)(dis + 100352);     // 100352
    int*   rp    = cnt + 100352;             // 100352 (needs 100001)
    int*   csr   = rp + 100352;              // 1600000
    int*   gcnt  = csr + 1600000;            // 1024
    int*   gptr  = gcnt + 1024;              // 1056 (needs 1025)
    int*   partN = gptr + 1056;              // 512
    int*   partG = partN + 512;              // 512
    int*   bcnt  = partG + 512;              // 64
    int*   flags = bcnt + 64;                // 16
    unsigned int* packed = (unsigned int*)(flags + 16);    // NB*BCAP = 2.62M (10.5 MB)
    unsigned short* bufA = (unsigned short*)(packed + NB * BCAP);  // bf16 xws (12.8 MB)
    float* bufB  = (float*)(bufA + 6400000);               // fp32 h (25.6 MB)

    const int TB = 256;
    dim3 blk(TB);
    int gN  = (N_NODES + TB - 1) / TB;       // 391
    int gG4 = (N_NODES + 3) / 4;             // 25000 (gather blocks)

    // wire-format detection
    k_detect<<<1, blk, 0, stream>>>((const unsigned int*)x, (const unsigned int*)ei, flags);

    // zero small counters (cnt is fully overwritten by k_hist; no big zero)
    k_zeroi<<<4, blk, 0, stream>>>(gcnt, 1024);
    k_zeroi<<<1, blk, 0, stream>>>(bcnt, NB);

    // phase A partition, then degrees from packed (LDS histogram)
    k_part<<<(N_EDGES + 1023) / 1024, blk, 0, stream>>>(ei, bcnt, packed, flags);
    k_hist<<<NB, 1024, 0, stream>>>(packed, bcnt, cnt);
    k_countb<<<gN, blk, 0, stream>>>(batch, gcnt, flags);
    k_disk<<<gN, blk, 0, stream>>>(cnt, dis);

    // CSR build: scans + XCD-pinned scatter
    k_scan_p1<<<gN, blk, 0, stream>>>(cnt, partN, N_NODES);
    k_scan_p2<<<1, 512, 0, stream>>>(partN, gN, rp, N_NODES);
    k_scan_p3<<<gN, blk, 0, stream>>>(cnt, partN, rp, N_NODES);
    k_scan_p1<<<4, blk, 0, stream>>>(gcnt, partG, N_GRAPHS);
    k_scan_p2<<<1, 512, 0, stream>>>(partG, 4, gptr, N_GRAPHS);
    k_scan_p3<<<4, blk, 0, stream>>>(gcnt, partG, gptr, N_GRAPHS);
    k_scatcsr<<<NB * BPB, blk, 0, stream>>>(packed, bcnt, rp, csr);  // rp -> end-ptrs

    // ---- layer 1 ----
    k_gemm<F_IN><<<1024, blk, 0, stream>>>(x, W1, dis, bufA, flags, -1);
    k_gather<<<gG4, blk, 0, stream>>>(rp, csr, dis, bufA, b1, bufB, 1, flags);
    // ---- layer 2 ----
    k_gemm<HID><<<1024, blk, 0, stream>>>(bufB, W2, dis, bufA, flags, 1);
    k_gather<<<gG4, blk, 0, stream>>>(rp, csr, dis, bufA, b2, bufB, 1, flags);
    // ---- layer 3 ----
    k_gemm<HID><<<1024, blk, 0, stream>>>(bufB, W3, dis, bufA, flags, 1);
    k_gather<<<gG4, blk, 0, stream>>>(rp, csr, dis, bufA, b3, bufB, 0, flags);

    // ---- pool + head ----
    k_pool_final<<<N_GRAPHS, 64, 0, stream>>>(gptr, bufB, Wl, bl, d_out, flags);
}

// Round 8
// 503.464 us; speedup vs baseline: 3.4297x; 1.1495x over previous
//
#include <hip/hip_runtime.h>
#include <hip/hip_bf16.h>

#define N_NODES 100000
#define N_EDGES 1600000
#define F_IN 128
#define HID 64
#define N_GRAPHS 1024

// coarse dst-partition for CSR build
#define NB 64          // buckets allocated (49 used: dst>>11)
#define BCAP 40960     // per-bucket capacity (mean 32768 + 45 sigma)
#define BPB 32         // blocks per bucket in phase B

typedef __attribute__((ext_vector_type(8))) short bf16x8;
typedef __attribute__((ext_vector_type(4))) float f32x4;

// ---------------- bf16 bit helpers --------------------------------------------
__device__ __forceinline__ unsigned short f2bf(float f) {
    __hip_bfloat16 h = __float2bfloat16(f);   // RNE
    return *reinterpret_cast<unsigned short*>(&h);
}
__device__ __forceinline__ float bf2f(unsigned int u) {
    return __uint_as_float(u << 16);
}

// ---------------- dual-path load helpers (wire dtype resolved at runtime) -----
__device__ __forceinline__ float loadf(const void* p, size_t i, int f32) {
    if (f32) return ((const float*)p)[i];
    return __bfloat162float(((const __hip_bfloat16*)p)[i]);
}
__device__ __forceinline__ int loadi(const void* p, size_t i, int i64) {
    if (i64) return (int)((const long long*)p)[i];
    return ((const int*)p)[i];
}

// ---------------- wire-format detector ----------------------------------------
__global__ void k_detect(const unsigned int* __restrict__ xw_,
                         const unsigned int* __restrict__ ei_,
                         int* __restrict__ flags) {
    __shared__ int cnt_f, cnt_i;
    if (threadIdx.x == 0) { cnt_f = 0; cnt_i = 0; }
    __syncthreads();
    unsigned int w = xw_[threadIdx.x];
    unsigned int e = (w >> 7) & 0xFFu;
    if (e >= 100u && e <= 140u) atomicAdd(&cnt_f, 1);
    unsigned int iw = ei_[2 * threadIdx.x + 1];
    if (iw == 0u) atomicAdd(&cnt_i, 1);
    __syncthreads();
    if (threadIdx.x == 0) {
        flags[0] = (cnt_f < 180) ? 1 : 0;   // 1 => fp32 wire
        flags[1] = (cnt_i >= 128) ? 1 : 0;  // 1 => int64 wire
    }
}

// ---------------- small utility kernels ---------------------------------------
__global__ void k_zeroi(int* p, int n) {
    int i = blockIdx.x * blockDim.x + threadIdx.x;
    if (i < n) p[i] = 0;
}

__global__ void k_countb(const void* __restrict__ batch, int* __restrict__ gcnt,
                         const int* __restrict__ flags) {
    int I64 = flags[1];
    int n = blockIdx.x * blockDim.x + threadIdx.x;
    if (n < N_NODES) atomicAdd(&gcnt[loadi(batch, n, I64)], 1);
}

__global__ void k_disk(const int* __restrict__ cnt, float* __restrict__ dis) {
    int i = blockIdx.x * blockDim.x + threadIdx.x;
    if (i < N_NODES) dis[i] = rsqrtf((float)cnt[i] + 1.0f);  // self-loop degree
}

// ---------------- hierarchical exclusive scan (3 phases) ----------------------
__global__ void k_scan_p1(const int* __restrict__ in, int* __restrict__ partial, int n) {
    __shared__ int s[256];
    int t = threadIdx.x;
    int i = blockIdx.x * 256 + t;
    s[t] = (i < n) ? in[i] : 0;
    __syncthreads();
    for (int off = 128; off > 0; off >>= 1) {
        if (t < off) s[t] += s[t + off];
        __syncthreads();
    }
    if (t == 0) partial[blockIdx.x] = s[0];
}

__global__ void k_scan_p2(int* __restrict__ partial, int nb,
                          int* __restrict__ out, int n) {
    __shared__ int s[512];
    int t = threadIdx.x;
    int v = (t < nb) ? partial[t] : 0;
    s[t] = v;
    __syncthreads();
    for (int off = 1; off < 512; off <<= 1) {
        int x = (t >= off) ? s[t - off] : 0;
        __syncthreads();
        s[t] += x;
        __syncthreads();
    }
    if (t < nb) partial[t] = s[t] - v;   // exclusive
    if (t == 511) out[n] = s[511];       // grand total
}

__global__ void k_scan_p3(const int* __restrict__ in, const int* __restrict__ partial,
                          int* __restrict__ out, int n) {
    __shared__ int s[256];
    int t = threadIdx.x;
    int i = blockIdx.x * 256 + t;
    int v = (i < n) ? in[i] : 0;
    s[t] = v;
    __syncthreads();
    for (int off = 1; off < 256; off <<= 1) {
        int x = (t >= off) ? s[t - off] : 0;
        __syncthreads();
        s[t] += x;
        __syncthreads();
    }
    if (i < n) out[i] = partial[blockIdx.x] + s[t] - v;
}

// ---------------- CSR build, phase A: coarse partition by dst>>11 -------------
__global__ __launch_bounds__(256) void k_part(const void* __restrict__ ei,
                                              int* __restrict__ bcnt,
                                              unsigned int* __restrict__ packed,
                                              const int* __restrict__ flags) {
    int I64 = flags[1];
    __shared__ int hist[NB];
    __shared__ int base[NB];
    int t = threadIdx.x;
    if (t < NB) hist[t] = 0;
    __syncthreads();
    int e0 = blockIdx.x * 1024;
    int b[4], r[4];
    unsigned int pk[4];
    for (int it = 0; it < 4; ++it) {
        int e = e0 + it * 256 + t;
        b[it] = -1;
        if (e < N_EDGES) {
            int s = loadi(ei, e, I64);
            int d = loadi(ei, (size_t)N_EDGES + e, I64);
            b[it] = d >> 11;
            pk[it] = ((unsigned int)s << 11) | (unsigned int)(d & 2047);
            r[it] = atomicAdd(&hist[b[it]], 1);   // LDS rank
        }
    }
    __syncthreads();
    if (t < NB) base[t] = hist[t] ? atomicAdd(&bcnt[t], hist[t]) : 0;
    __syncthreads();
    for (int it = 0; it < 4; ++it) {
        if (b[it] >= 0) {
            int pos = base[b[it]] + r[it];
            if (pos < BCAP) packed[(size_t)b[it] * BCAP + pos] = pk[it];
        }
    }
}

// ---------------- in-degree from packed: per-bucket LDS histogram -------------
__global__ __launch_bounds__(1024) void k_hist(const unsigned int* __restrict__ packed,
                                               const int* __restrict__ bcnt,
                                               int* __restrict__ cnt) {
    __shared__ int hist[2048];
    int b = blockIdx.x;
    int n = bcnt[b];
    if (n > BCAP) n = BCAP;
    for (int i = threadIdx.x; i < 2048; i += 1024) hist[i] = 0;
    __syncthreads();
    const unsigned int* pb = packed + (size_t)b * BCAP;
    for (int i = threadIdx.x; i < n; i += 1024)
        atomicAdd(&hist[pb[i] & 2047u], 1);
    __syncthreads();
    int nbase = b << 11;
    for (int i = threadIdx.x; i < 2048; i += 1024) {
        int node = nbase + i;
        if (node < N_NODES) cnt[node] = hist[i];
    }
}

// ---------------- CSR build, phase B: XCD-pinned per-bucket scatter ----------
__global__ __launch_bounds__(256) void k_scatcsr(const unsigned int* __restrict__ packed,
                                                 const int* __restrict__ bcnt,
                                                 int* __restrict__ rp,
                                                 int* __restrict__ csr) {
    int xcd = blockIdx.x & 7;
    int m = blockIdx.x >> 3;
    int b = 8 * (m / BPB) + xcd;      // all BPB blocks of bucket b on one XCD
    int sub = m % BPB;
    int n = bcnt[b];
    if (n > BCAP) n = BCAP;
    const unsigned int* pb = packed + (size_t)b * BCAP;
    for (int i = sub * 256 + threadIdx.x; i < n; i += BPB * 256) {
        unsigned int p = pb[i];
        int s = (int)(p >> 11);
        int d = (b << 11) | (int)(p & 2047u);
        int pos = atomicAdd(&rp[d], 1);
        csr[pos] = s;
    }
}

// ---------------- MFMA GEMM: in[N,K] @ W[K,64] -> out[N,64] bf16, x dis[row] --
// Block = 4 waves; wave w owns cols [16w,16w+16). W^T in LDS (row pad +8 ushorts
// -> b128 reads hit the 8-cyc bank floor, no conflicts). B-frags in registers.
// Per block-iter: 32 rows, 2 row-tiles/wave, K/32 MFMAs each.
// Frag layouts (verified m89/m91/m120): A[m=lane&15][k=quad*8+j];
// B from W^T symmetric; C/D col=lane&15, row=quad*4+reg.
template <int K>
__global__ __launch_bounds__(256) void k_gemm(const void* __restrict__ x,
                                              const void* __restrict__ W,
                                              const float* __restrict__ dis,
                                              unsigned short* __restrict__ out,  // bf16 bits
                                              const int* __restrict__ flags,
                                              int x_is_f32) {
    int Wf32 = flags[0];
    int xF32 = (x_is_f32 < 0) ? Wf32 : x_is_f32;
    __shared__ unsigned short Wt[64][K + 8];
    __shared__ unsigned short xs[32][K + 8];
    int t = threadIdx.x;
    int wave = t >> 6, lane = t & 63;
    int quad = lane >> 4, l16 = lane & 15;

    // stage W^T (once per block)
    for (int id = t; id < 64 * K; id += 256) {
        int k = id >> 6, n = id & 63;
        Wt[n][k] = f2bf(loadf(W, id, Wf32));
    }
    __syncthreads();

    // B-frags into registers: lane holds Wt[wave*16+l16][c*32+quad*8 .. +7]
    bf16x8 bfrag[K / 32];
#pragma unroll
    for (int c = 0; c < K / 32; ++c)
        bfrag[c] = *reinterpret_cast<bf16x8*>(&Wt[wave * 16 + l16][c * 32 + quad * 8]);

    const int ngroups = (N_NODES + 31) / 32;   // 3125, exact
    for (int g = blockIdx.x; g < ngroups; g += gridDim.x) {
        __syncthreads();   // xs reuse
        int row0 = g * 32;
        // stage 32 rows of A as bf16 (8-ushort chunks; 4*K/8 chunks total)
        for (int cid = t; cid < 4 * K; cid += 256) {
            int rr = cid / (K / 8), c8 = cid % (K / 8);
            int r = row0 + rr;
            uint4 val = make_uint4(0, 0, 0, 0);
            if (r < N_NODES) {
                size_t base = (size_t)r * K + c8 * 8;
                if (xF32) {
                    float4 p0 = ((const float4*)x)[base / 4];
                    float4 p1 = ((const float4*)x)[base / 4 + 1];
                    val.x = f2bf(p0.x) | ((unsigned int)f2bf(p0.y) << 16);
                    val.y = f2bf(p0.z) | ((unsigned int)f2bf(p0.w) << 16);
                    val.z = f2bf(p1.x) | ((unsigned int)f2bf(p1.y) << 16);
                    val.w = f2bf(p1.z) | ((unsigned int)f2bf(p1.w) << 16);
                } else {
                    val = ((const uint4*)x)[base / 8];
                }
            }
            *reinterpret_cast<uint4*>(&xs[rr][c8 * 8]) = val;
        }
        __syncthreads();

        f32x4 acc0 = {0.f, 0.f, 0.f, 0.f};
        f32x4 acc1 = {0.f, 0.f, 0.f, 0.f};
#pragma unroll
        for (int c = 0; c < K / 32; ++c) {
            bf16x8 a0 = *reinterpret_cast<bf16x8*>(&xs[l16][c * 32 + quad * 8]);
            bf16x8 a1 = *reinterpret_cast<bf16x8*>(&xs[16 + l16][c * 32 + quad * 8]);
            acc0 = __builtin_amdgcn_mfma_f32_16x16x32_bf16(a0, bfrag[c], acc0, 0, 0, 0);
            acc1 = __builtin_amdgcn_mfma_f32_16x16x32_bf16(a1, bfrag[c], acc1, 0, 0, 0);
        }
        int col = wave * 16 + l16;
#pragma unroll
        for (int reg = 0; reg < 4; ++reg) {
            int r0 = row0 + quad * 4 + reg;
            if (r0 < N_NODES) out[(size_t)r0 * 64 + col] = f2bf(acc0[reg] * dis[r0]);
            int r1 = row0 + 16 + quad * 4 + reg;
            if (r1 < N_NODES) out[(size_t)r1 * 64 + col] = f2bf(acc1[reg] * dis[r1]);
        }
    }
}

// ---------------- fused gather + self-loop + bias + relu (bf16 in/out) --------
__global__ __launch_bounds__(256) void k_gather(const int* __restrict__ rp_end,
                                                const int* __restrict__ csr,
                                                const float* __restrict__ dis,
                                                const unsigned short* __restrict__ xws,
                                                const void* __restrict__ b,
                                                unsigned short* __restrict__ out,
                                                int do_relu,
                                                const int* __restrict__ flags) {
    int F32 = flags[0];
    int wave = threadIdx.x >> 6, lane = threadIdx.x & 63;
    int node = blockIdx.x * 4 + wave;
    if (node >= N_NODES) return;
    int f4 = lane & 15, nsub = lane >> 4;
    int start = (node == 0) ? 0 : rp_end[node - 1];
    int end = rp_end[node];
    const ushort4* x4 = (const ushort4*)xws;
    float ax = 0, ay = 0, az = 0, aw = 0;
    int j = start + nsub;
    if (j < end) {
        int s = csr[j];
        for (j += 4; j < end; j += 4) {
            int snext = csr[j];                       // prefetch next index
            ushort4 v = x4[(size_t)s * 16 + f4];
            ax += bf2f(v.x); ay += bf2f(v.y); az += bf2f(v.z); aw += bf2f(v.w);
            s = snext;
        }
        ushort4 v = x4[(size_t)s * 16 + f4];
        ax += bf2f(v.x); ay += bf2f(v.y); az += bf2f(v.z); aw += bf2f(v.w);
    }
    ax += __shfl_down(ax, 32, 64); ay += __shfl_down(ay, 32, 64);
    az += __shfl_down(az, 32, 64); aw += __shfl_down(aw, 32, 64);
    ax += __shfl_down(ax, 16, 64); ay += __shfl_down(ay, 16, 64);
    az += __shfl_down(az, 16, 64); aw += __shfl_down(aw, 16, 64);
    if (nsub == 0) {
        ushort4 sv = x4[(size_t)node * 16 + f4];
        float dn = dis[node];
        float vx = fmaf(ax + bf2f(sv.x), dn, loadf(b, 4 * f4 + 0, F32));
        float vy = fmaf(ay + bf2f(sv.y), dn, loadf(b, 4 * f4 + 1, F32));
        float vz = fmaf(az + bf2f(sv.z), dn, loadf(b, 4 * f4 + 2, F32));
        float vw = fmaf(aw + bf2f(sv.w), dn, loadf(b, 4 * f4 + 3, F32));
        if (do_relu) {
            vx = fmaxf(vx, 0.0f); vy = fmaxf(vy, 0.0f);
            vz = fmaxf(vz, 0.0f); vw = fmaxf(vw, 0.0f);
        }
        ushort4 o;
        o.x = f2bf(vx); o.y = f2bf(vy); o.z = f2bf(vz); o.w = f2bf(vw);
        ((ushort4*)out)[(size_t)node * 16 + f4] = o;
    }
}

// ---------------- fused mean-pool + linear head (bf16 h) ----------------------
__global__ void k_pool_final(const int* __restrict__ gptr,
                             const unsigned short* __restrict__ h,
                             const void* __restrict__ Wl, const void* __restrict__ bl,
                             void* __restrict__ out, const int* __restrict__ flags) {
    int F32 = flags[0];
    int g = blockIdx.x;
    int lane = threadIdx.x;  // 64
    int s = gptr[g], e = gptr[g + 1];
    float acc = 0.0f;
    for (int n = s; n < e; ++n) acc += bf2f(h[(size_t)n * HID + lane]);
    float cnt = fmaxf((float)(e - s), 1.0f);
    float v = (acc / cnt) * loadf(Wl, lane, F32);
#pragma unroll
    for (int o = 32; o > 0; o >>= 1) v += __shfl_down(v, o, 64);
    if (lane == 0) {
        float r = v + loadf(bl, 0, F32);
        if (F32) ((float*)out)[g] = r;
        else     ((__hip_bfloat16*)out)[g] = __float2bfloat16(r);
    }
}

extern "C" void kernel_launch(void* const* d_in, const int* in_sizes, int n_in,
                              void* d_out, int out_size, void* d_ws, size_t ws_size,
                              hipStream_t stream) {
    const void* x     = d_in[0];
    const void* ei    = d_in[1];
    const void* batch = d_in[2];
    const void* W1 = d_in[3];
    const void* b1 = d_in[4];
    const void* W2 = d_in[5];
    const void* b2 = d_in[6];
    const void* W3 = d_in[7];
    const void* b3 = d_in[8];
    const void* Wl = d_in[9];
    const void* bl = d_in[10];

    // workspace layout (~43.7 MB)
    float* dis   = (float*)d_ws;             // 100352
    int*   cnt   = (int*)(dis + 100352);     // 100352
    int*   rp    = cnt + 100352;             // 100352 (needs 100001)
    int*   csr   = rp + 100352;              // 1600000
    int*   gcnt  = csr + 1600000;            // 1024
    int*   gptr  = gcnt + 1024;              // 1056 (needs 1025)
    int*   partN = gptr + 1056;              // 512
    int*   partG = partN + 512;              // 512
    int*   bcnt  = partG + 512;              // 64
    int*   flags = bcnt + 64;                // 16
    unsigned int* packed = (unsigned int*)(flags + 16);    // NB*BCAP (10.5 MB)
    unsigned short* bufA = (unsigned short*)(packed + NB * BCAP);  // bf16 xws (12.8 MB)
    unsigned short* bufB = bufA + 6400000;                 // bf16 h (12.8 MB)

    const int TB = 256;
    dim3 blk(TB);
    int gN  = (N_NODES + TB - 1) / TB;       // 391
    int gG4 = (N_NODES + 3) / 4;             // 25000 (gather blocks)

    // wire-format detection
    k_detect<<<1, blk, 0, stream>>>((const unsigned int*)x, (const unsigned int*)ei, flags);

    // zero small counters
    k_zeroi<<<4, blk, 0, stream>>>(gcnt, 1024);
    k_zeroi<<<1, blk, 0, stream>>>(bcnt, NB);

    // phase A partition, then degrees from packed (LDS histogram)
    k_part<<<(N_EDGES + 1023) / 1024, blk, 0, stream>>>(ei, bcnt, packed, flags);
    k_hist<<<NB, 1024, 0, stream>>>(packed, bcnt, cnt);
    k_countb<<<gN, blk, 0, stream>>>(batch, gcnt, flags);
    k_disk<<<gN, blk, 0, stream>>>(cnt, dis);

    // CSR build: scans + XCD-pinned scatter
    k_scan_p1<<<gN, blk, 0, stream>>>(cnt, partN, N_NODES);
    k_scan_p2<<<1, 512, 0, stream>>>(partN, gN, rp, N_NODES);
    k_scan_p3<<<gN, blk, 0, stream>>>(cnt, partN, rp, N_NODES);
    k_scan_p1<<<4, blk, 0, stream>>>(gcnt, partG, N_GRAPHS);
    k_scan_p2<<<1, 512, 0, stream>>>(partG, 4, gptr, N_GRAPHS);
    k_scan_p3<<<4, blk, 0, stream>>>(gcnt, partG, gptr, N_GRAPHS);
    k_scatcsr<<<NB * BPB, blk, 0, stream>>>(packed, bcnt, rp, csr);  // rp -> end-ptrs

    // ---- layer 1 ----
    k_gemm<F_IN><<<1024, blk, 0, stream>>>(x, W1, dis, bufA, flags, -1);
    k_gather<<<gG4, blk, 0, stream>>>(rp, csr, dis, bufA, b1, bufB, 1, flags);
    // ---- layer 2 ----
    k_gemm<HID><<<1024, blk, 0, stream>>>(bufB, W2, dis, bufA, flags, 0);
    k_gather<<<gG4, blk, 0, stream>>>(rp, csr, dis, bufA, b2, bufB, 1, flags);
    // ---- layer 3 ----
    k_gemm<HID><<<1024, blk, 0, stream>>>(bufB, W3, dis, bufA, flags, 0);
    k_gather<<<gG4, blk, 0, stream>>>(rp, csr, dis, bufA, b3, bufB, 0, flags);

    // ---- pool + head ----
    k_pool_final<<<N_GRAPHS, 64, 0, stream>>>(gptr, bufB, Wl, bl, d_out, flags);
}

// Round 9
// 468.458 us; speedup vs baseline: 3.6860x; 1.0747x over previous
//
#include <hip/hip_runtime.h>
#include <hip/hip_bf16.h>

#define N_NODES 100000
#define N_EDGES 1600000
#define F_IN 128
#define HID 64
#define N_GRAPHS 1024

// fine dst-partition for CSR build: bucket = dst>>9 (512 nodes/bucket)
#define SH 9
#define NBU 196        // buckets used: ceil(100000/512)
#define NB 200         // allocated
#define BCAP 9728      // mean 8192 + 17 sigma

typedef __attribute__((ext_vector_type(8))) short bf16x8;
typedef __attribute__((ext_vector_type(4))) float f32x4;

// ---------------- bf16 bit helpers --------------------------------------------
__device__ __forceinline__ unsigned short f2bf(float f) {
    __hip_bfloat16 h = __float2bfloat16(f);   // RNE
    return *reinterpret_cast<unsigned short*>(&h);
}
__device__ __forceinline__ float bf2f(unsigned int u) {
    return __uint_as_float(u << 16);
}

// ---------------- dual-path load helpers (wire dtype resolved at runtime) -----
__device__ __forceinline__ float loadf(const void* p, size_t i, int f32) {
    if (f32) return ((const float*)p)[i];
    return __bfloat162float(((const __hip_bfloat16*)p)[i]);
}
__device__ __forceinline__ int loadi(const void* p, size_t i, int i64) {
    if (i64) return (int)((const long long*)p)[i];
    return ((const int*)p)[i];
}

// ---------------- wire-format detector ----------------------------------------
__global__ void k_detect(const unsigned int* __restrict__ xw_,
                         const unsigned int* __restrict__ ei_,
                         int* __restrict__ flags) {
    __shared__ int cnt_f, cnt_i;
    if (threadIdx.x == 0) { cnt_f = 0; cnt_i = 0; }
    __syncthreads();
    unsigned int w = xw_[threadIdx.x];
    unsigned int e = (w >> 7) & 0xFFu;
    if (e >= 100u && e <= 140u) atomicAdd(&cnt_f, 1);
    unsigned int iw = ei_[2 * threadIdx.x + 1];
    if (iw == 0u) atomicAdd(&cnt_i, 1);
    __syncthreads();
    if (threadIdx.x == 0) {
        flags[0] = (cnt_f < 180) ? 1 : 0;   // 1 => fp32 wire
        flags[1] = (cnt_i >= 128) ? 1 : 0;  // 1 => int64 wire
    }
}

// ---------------- small utility kernels ---------------------------------------
__global__ void k_zeroi(int* p, int n) {
    int i = blockIdx.x * blockDim.x + threadIdx.x;
    if (i < n) p[i] = 0;
}

__global__ void k_countb(const void* __restrict__ batch, int* __restrict__ gcnt,
                         const int* __restrict__ flags) {
    int I64 = flags[1];
    int n = blockIdx.x * blockDim.x + threadIdx.x;
    if (n < N_NODES) atomicAdd(&gcnt[loadi(batch, n, I64)], 1);
}

__global__ void k_disk(const int* __restrict__ cnt, float* __restrict__ dis) {
    int i = blockIdx.x * blockDim.x + threadIdx.x;
    if (i < N_NODES) dis[i] = rsqrtf((float)cnt[i] + 1.0f);  // self-loop degree
}

// ---------------- hierarchical exclusive scan (3 phases) ----------------------
__global__ void k_scan_p1(const int* __restrict__ in, int* __restrict__ partial, int n) {
    __shared__ int s[256];
    int t = threadIdx.x;
    int i = blockIdx.x * 256 + t;
    s[t] = (i < n) ? in[i] : 0;
    __syncthreads();
    for (int off = 128; off > 0; off >>= 1) {
        if (t < off) s[t] += s[t + off];
        __syncthreads();
    }
    if (t == 0) partial[blockIdx.x] = s[0];
}

__global__ void k_scan_p2(int* __restrict__ partial, int nb,
                          int* __restrict__ out, int n) {
    __shared__ int s[512];
    int t = threadIdx.x;
    int v = (t < nb) ? partial[t] : 0;
    s[t] = v;
    __syncthreads();
    for (int off = 1; off < 512; off <<= 1) {
        int x = (t >= off) ? s[t - off] : 0;
        __syncthreads();
        s[t] += x;
        __syncthreads();
    }
    if (t < nb) partial[t] = s[t] - v;   // exclusive
    if (t == 511) out[n] = s[511];       // grand total
}

__global__ void k_scan_p3(const int* __restrict__ in, const int* __restrict__ partial,
                          int* __restrict__ out, int n) {
    __shared__ int s[256];
    int t = threadIdx.x;
    int i = blockIdx.x * 256 + t;
    int v = (i < n) ? in[i] : 0;
    s[t] = v;
    __syncthreads();
    for (int off = 1; off < 256; off <<= 1) {
        int x = (t >= off) ? s[t - off] : 0;
        __syncthreads();
        s[t] += x;
        __syncthreads();
    }
    if (i < n) out[i] = partial[blockIdx.x] + s[t] - v;
}

// ---------------- CSR build, phase A: partition by dst>>9 ---------------------
// packed entry: (src << 9) | (dst & 511)  -- 26 bits.
__global__ __launch_bounds__(256) void k_part(const void* __restrict__ ei,
                                              int* __restrict__ bcnt,
                                              unsigned int* __restrict__ packed,
                                              const int* __restrict__ flags) {
    int I64 = flags[1];
    __shared__ int hist[NB];
    __shared__ int base[NB];
    int t = threadIdx.x;
    if (t < NB) hist[t] = 0;
    __syncthreads();
    int e0 = blockIdx.x * 1024;
    int b[4], r[4];
    unsigned int pk[4];
    for (int it = 0; it < 4; ++it) {
        int e = e0 + it * 256 + t;
        b[it] = -1;
        if (e < N_EDGES) {
            int s = loadi(ei, e, I64);
            int d = loadi(ei, (size_t)N_EDGES + e, I64);
            b[it] = d >> SH;
            pk[it] = ((unsigned int)s << SH) | (unsigned int)(d & 511);
            r[it] = atomicAdd(&hist[b[it]], 1);   // LDS rank
        }
    }
    __syncthreads();
    if (t < NB) base[t] = hist[t] ? atomicAdd(&bcnt[t], hist[t]) : 0;
    __syncthreads();
    for (int it = 0; it < 4; ++it) {
        if (b[it] >= 0) {
            int pos = base[b[it]] + r[it];
            if (pos < BCAP) packed[(size_t)b[it] * BCAP + pos] = pk[it];
        }
    }
}

// ---------------- in-degree from packed: per-bucket LDS histogram -------------
__global__ __launch_bounds__(256) void k_hist(const unsigned int* __restrict__ packed,
                                              const int* __restrict__ bcnt,
                                              int* __restrict__ cnt) {
    __shared__ int hist[512];
    int b = blockIdx.x;
    int n = bcnt[b];
    if (n > BCAP) n = BCAP;
    for (int i = threadIdx.x; i < 512; i += 256) hist[i] = 0;
    __syncthreads();
    const unsigned int* pb = packed + (size_t)b * BCAP;
    for (int i = threadIdx.x; i < n; i += 256)
        atomicAdd(&hist[pb[i] & 511u], 1);
    __syncthreads();
    int nbase = b << SH;
    for (int i = threadIdx.x; i < 512; i += 256) {
        int node = nbase + i;
        if (node < N_NODES) cnt[node] = hist[i];
    }
}

// ---------------- CSR build, phase B: LDS counting-sort, dense writes ---------
// One block per bucket: offs from pristine rp, LDS-atomic rank, scatter into
// LDS, then fully-coalesced copy-out. No random global stores at all.
__global__ __launch_bounds__(512) void k_bucketcsr(const unsigned int* __restrict__ packed,
                                                   const int* __restrict__ bcnt,
                                                   const int* __restrict__ rp,
                                                   int* __restrict__ csr) {
    __shared__ int offs[512];
    __shared__ int elds[BCAP];    // 38 KB
    int b = blockIdx.x;
    int nbase = b << SH;
    int base = rp[nbase];
    int lim = nbase + 512; if (lim > N_NODES) lim = N_NODES;
    int nedge = rp[lim] - base;
    if (nedge > BCAP) nedge = BCAP;
    for (int i = threadIdx.x; i < 512; i += 512) {
        int node = nbase + i;
        offs[i] = (node < N_NODES) ? (rp[node] - base) : nedge;
    }
    __syncthreads();
    int n = bcnt[b]; if (n > BCAP) n = BCAP;
    const unsigned int* pb = packed + (size_t)b * BCAP;
    for (int i = threadIdx.x; i < n; i += 512) {
        unsigned int p = pb[i];
        int pos = atomicAdd(&offs[p & 511u], 1);
        if (pos < BCAP) elds[pos] = (int)(p >> SH);
    }
    __syncthreads();
    for (int i = threadIdx.x; i < nedge; i += 512)
        csr[base + i] = elds[i];
}

// ---------------- MFMA GEMM: in[N,K] @ W[K,64] -> out[N,64] bf16, x dis[row] --
template <int K>
__global__ __launch_bounds__(256) void k_gemm(const void* __restrict__ x,
                                              const void* __restrict__ W,
                                              const float* __restrict__ dis,
                                              unsigned short* __restrict__ out,  // bf16 bits
                                              const int* __restrict__ flags,
                                              int x_is_f32) {
    int Wf32 = flags[0];
    int xF32 = (x_is_f32 < 0) ? Wf32 : x_is_f32;
    __shared__ unsigned short Wt[64][K + 8];
    __shared__ unsigned short xs[32][K + 8];
    int t = threadIdx.x;
    int wave = t >> 6, lane = t & 63;
    int quad = lane >> 4, l16 = lane & 15;

    for (int id = t; id < 64 * K; id += 256) {
        int k = id >> 6, n = id & 63;
        Wt[n][k] = f2bf(loadf(W, id, Wf32));
    }
    __syncthreads();

    bf16x8 bfrag[K / 32];
#pragma unroll
    for (int c = 0; c < K / 32; ++c)
        bfrag[c] = *reinterpret_cast<bf16x8*>(&Wt[wave * 16 + l16][c * 32 + quad * 8]);

    const int ngroups = (N_NODES + 31) / 32;
    for (int g = blockIdx.x; g < ngroups; g += gridDim.x) {
        __syncthreads();
        int row0 = g * 32;
        for (int cid = t; cid < 4 * K; cid += 256) {
            int rr = cid / (K / 8), c8 = cid % (K / 8);
            int r = row0 + rr;
            uint4 val = make_uint4(0, 0, 0, 0);
            if (r < N_NODES) {
                size_t base = (size_t)r * K + c8 * 8;
                if (xF32) {
                    float4 p0 = ((const float4*)x)[base / 4];
                    float4 p1 = ((const float4*)x)[base / 4 + 1];
                    val.x = f2bf(p0.x) | ((unsigned int)f2bf(p0.y) << 16);
                    val.y = f2bf(p0.z) | ((unsigned int)f2bf(p0.w) << 16);
                    val.z = f2bf(p1.x) | ((unsigned int)f2bf(p1.y) << 16);
                    val.w = f2bf(p1.z) | ((unsigned int)f2bf(p1.w) << 16);
                } else {
                    val = ((const uint4*)x)[base / 8];
                }
            }
            *reinterpret_cast<uint4*>(&xs[rr][c8 * 8]) = val;
        }
        __syncthreads();

        f32x4 acc0 = {0.f, 0.f, 0.f, 0.f};
        f32x4 acc1 = {0.f, 0.f, 0.f, 0.f};
#pragma unroll
        for (int c = 0; c < K / 32; ++c) {
            bf16x8 a0 = *reinterpret_cast<bf16x8*>(&xs[l16][c * 32 + quad * 8]);
            bf16x8 a1 = *reinterpret_cast<bf16x8*>(&xs[16 + l16][c * 32 + quad * 8]);
            acc0 = __builtin_amdgcn_mfma_f32_16x16x32_bf16(a0, bfrag[c], acc0, 0, 0, 0);
            acc1 = __builtin_amdgcn_mfma_f32_16x16x32_bf16(a1, bfrag[c], acc1, 0, 0, 0);
        }
        int col = wave * 16 + l16;
#pragma unroll
        for (int reg = 0; reg < 4; ++reg) {
            int r0 = row0 + quad * 4 + reg;
            if (r0 < N_NODES) out[(size_t)r0 * 64 + col] = f2bf(acc0[reg] * dis[r0]);
            int r1 = row0 + 16 + quad * 4 + reg;
            if (r1 < N_NODES) out[(size_t)r1 * 64 + col] = f2bf(acc1[reg] * dis[r1]);
        }
    }
}

// ---------------- fused gather + self-loop + bias + relu (bf16 in/out) --------
// Wave = node; lane = nsub*8 + f8: 8 neighbor rows in flight (uint4 = 8 bf16
// per lane, 8 lanes = 128 B row). 3-stage shfl reduce over nsub.
__global__ __launch_bounds__(256) void k_gather(const int* __restrict__ rp,
                                                const int* __restrict__ csr,
                                                const float* __restrict__ dis,
                                                const unsigned short* __restrict__ xws,
                                                const void* __restrict__ b,
                                                unsigned short* __restrict__ out,
                                                int do_relu,
                                                const int* __restrict__ flags) {
    int F32 = flags[0];
    int wave = threadIdx.x >> 6, lane = threadIdx.x & 63;
    int node = blockIdx.x * 4 + wave;
    if (node >= N_NODES) return;
    int f8 = lane & 7, nsub = lane >> 3;
    int start = rp[node], end = rp[node + 1];
    const uint4* x8 = (const uint4*)xws;   // row = 8 uint4 (128 B)
    float a0 = 0, a1 = 0, a2 = 0, a3 = 0, a4 = 0, a5 = 0, a6 = 0, a7 = 0;
    for (int j = start + nsub; j < end; j += 8) {
        int s = csr[j];
        uint4 v = x8[(size_t)s * 8 + f8];
        a0 += bf2f(v.x & 0xFFFFu); a1 += bf2f(v.x >> 16);
        a2 += bf2f(v.y & 0xFFFFu); a3 += bf2f(v.y >> 16);
        a4 += bf2f(v.z & 0xFFFFu); a5 += bf2f(v.z >> 16);
        a6 += bf2f(v.w & 0xFFFFu); a7 += bf2f(v.w >> 16);
    }
#pragma unroll
    for (int off = 32; off >= 8; off >>= 1) {
        a0 += __shfl_down(a0, off, 64); a1 += __shfl_down(a1, off, 64);
        a2 += __shfl_down(a2, off, 64); a3 += __shfl_down(a3, off, 64);
        a4 += __shfl_down(a4, off, 64); a5 += __shfl_down(a5, off, 64);
        a6 += __shfl_down(a6, off, 64); a7 += __shfl_down(a7, off, 64);
    }
    if (nsub == 0) {
        uint4 sv = x8[(size_t)node * 8 + f8];
        float dn = dis[node];
        float v0 = fmaf(a0 + bf2f(sv.x & 0xFFFFu), dn, loadf(b, 8 * f8 + 0, F32));
        float v1 = fmaf(a1 + bf2f(sv.x >> 16),     dn, loadf(b, 8 * f8 + 1, F32));
        float v2 = fmaf(a2 + bf2f(sv.y & 0xFFFFu), dn, loadf(b, 8 * f8 + 2, F32));
        float v3 = fmaf(a3 + bf2f(sv.y >> 16),     dn, loadf(b, 8 * f8 + 3, F32));
        float v4 = fmaf(a4 + bf2f(sv.z & 0xFFFFu), dn, loadf(b, 8 * f8 + 4, F32));
        float v5 = fmaf(a5 + bf2f(sv.z >> 16),     dn, loadf(b, 8 * f8 + 5, F32));
        float v6 = fmaf(a6 + bf2f(sv.w & 0xFFFFu), dn, loadf(b, 8 * f8 + 6, F32));
        float v7 = fmaf(a7 + bf2f(sv.w >> 16),     dn, loadf(b, 8 * f8 + 7, F32));
        if (do_relu) {
            v0 = fmaxf(v0, 0.f); v1 = fmaxf(v1, 0.f); v2 = fmaxf(v2, 0.f); v3 = fmaxf(v3, 0.f);
            v4 = fmaxf(v4, 0.f); v5 = fmaxf(v5, 0.f); v6 = fmaxf(v6, 0.f); v7 = fmaxf(v7, 0.f);
        }
        uint4 o;
        o.x = f2bf(v0) | ((unsigned int)f2bf(v1) << 16);
        o.y = f2bf(v2) | ((unsigned int)f2bf(v3) << 16);
        o.z = f2bf(v4) | ((unsigned int)f2bf(v5) << 16);
        o.w = f2bf(v6) | ((unsigned int)f2bf(v7) << 16);
        ((uint4*)out)[(size_t)node * 8 + f8] = o;
    }
}

// ---------------- fused mean-pool + linear head (bf16 h) ----------------------
__global__ void k_pool_final(const int* __restrict__ gptr,
                             const unsigned short* __restrict__ h,
                             const void* __restrict__ Wl, const void* __restrict__ bl,
                             void* __restrict__ out, const int* __restrict__ flags) {
    int F32 = flags[0];
    int g = blockIdx.x;
    int lane = threadIdx.x;  // 64
    int s = gptr[g], e = gptr[g + 1];
    float acc = 0.0f;
    for (int n = s; n < e; ++n) acc += bf2f(h[(size_t)n * HID + lane]);
    float cnt = fmaxf((float)(e - s), 1.0f);
    float v = (acc / cnt) * loadf(Wl, lane, F32);
#pragma unroll
    for (int o = 32; o > 0; o >>= 1) v += __shfl_down(v, o, 64);
    if (lane == 0) {
        float r = v + loadf(bl, 0, F32);
        if (F32) ((float*)out)[g] = r;
        else     ((__hip_bfloat16*)out)[g] = __float2bfloat16(r);
    }
}

extern "C" void kernel_launch(void* const* d_in, const int* in_sizes, int n_in,
                              void* d_out, int out_size, void* d_ws, size_t ws_size,
                              hipStream_t stream) {
    const void* x     = d_in[0];
    const void* ei    = d_in[1];
    const void* batch = d_in[2];
    const void* W1 = d_in[3];
    const void* b1 = d_in[4];
    const void* W2 = d_in[5];
    const void* b2 = d_in[6];
    const void* W3 = d_in[7];
    const void* b3 = d_in[8];
    const void* Wl = d_in[9];
    const void* bl = d_in[10];

    // workspace layout (~41 MB)
    float* dis   = (float*)d_ws;             // 100352
    int*   cnt   = (int*)(dis + 100352);     // 100352
    int*   rp    = cnt + 100352;             // 100352 (needs 100001)
    int*   csr   = rp + 100352;              // 1600000
    int*   gcnt  = csr + 1600000;            // 1024
    int*   gptr  = gcnt + 1024;              // 1056 (needs 1025)
    int*   partN = gptr + 1056;              // 512
    int*   partG = partN + 512;              // 512
    int*   bcnt  = partG + 512;              // 256
    int*   flags = bcnt + 256;               // 16
    unsigned int* packed = (unsigned int*)(flags + 16);    // NB*BCAP (7.8 MB)
    unsigned short* bufA = (unsigned short*)(packed + (size_t)NB * BCAP);  // bf16 xws (12.8 MB)
    unsigned short* bufB = bufA + 6400000;                 // bf16 h (12.8 MB)

    const int TB = 256;
    dim3 blk(TB);
    int gN  = (N_NODES + TB - 1) / TB;       // 391
    int gG4 = (N_NODES + 3) / 4;             // 25000 (gather blocks)

    // wire-format detection
    k_detect<<<1, blk, 0, stream>>>((const unsigned int*)x, (const unsigned int*)ei, flags);

    // zero small counters
    k_zeroi<<<4, blk, 0, stream>>>(gcnt, 1024);
    k_zeroi<<<1, blk, 0, stream>>>(bcnt, NB);

    // phase A partition, then degrees from packed (LDS histogram)
    k_part<<<(N_EDGES + 1023) / 1024, blk, 0, stream>>>(ei, bcnt, packed, flags);
    k_hist<<<NBU, blk, 0, stream>>>(packed, bcnt, cnt);
    k_countb<<<gN, blk, 0, stream>>>(batch, gcnt, flags);
    k_disk<<<gN, blk, 0, stream>>>(cnt, dis);

    // scans (rp stays pristine start-offsets; rp[N] = total)
    k_scan_p1<<<gN, blk, 0, stream>>>(cnt, partN, N_NODES);
    k_scan_p2<<<1, 512, 0, stream>>>(partN, gN, rp, N_NODES);
    k_scan_p3<<<gN, blk, 0, stream>>>(cnt, partN, rp, N_NODES);
    k_scan_p1<<<4, blk, 0, stream>>>(gcnt, partG, N_GRAPHS);
    k_scan_p2<<<1, 512, 0, stream>>>(partG, 4, gptr, N_GRAPHS);
    k_scan_p3<<<4, blk, 0, stream>>>(gcnt, partG, gptr, N_GRAPHS);

    // phase B: LDS counting-sort per bucket, dense csr writes
    k_bucketcsr<<<NBU, 512, 0, stream>>>(packed, bcnt, rp, csr);

    // ---- layer 1 ----
    k_gemm<F_IN><<<1024, blk, 0, stream>>>(x, W1, dis, bufA, flags, -1);
    k_gather<<<gG4, blk, 0, stream>>>(rp, csr, dis, bufA, b1, bufB, 1, flags);
    // ---- layer 2 ----
    k_gemm<HID><<<1024, blk, 0, stream>>>(bufB, W2, dis, bufA, flags, 0);
    k_gather<<<gG4, blk, 0, stream>>>(rp, csr, dis, bufA, b2, bufB, 1, flags);
    // ---- layer 3 ----
    k_gemm<HID><<<1024, blk, 0, stream>>>(bufB, W3, dis, bufA, flags, 0);
    k_gather<<<gG4, blk, 0, stream>>>(rp, csr, dis, bufA, b3, bufB, 0, flags);

    // ---- pool + head ----
    k_pool_final<<<N_GRAPHS, 64, 0, stream>>>(gptr, bufB, Wl, bl, d_out, flags);
}